// Round 17
// baseline (273.642 us; speedup 1.0000x reference)
//
#include <hip/hip_runtime.h>

#define DEVI __device__ __forceinline__

typedef __attribute__((ext_vector_type(4))) float f32x4;
typedef __attribute__((ext_vector_type(8))) short bf16x8;

DEVI unsigned short f2bf(float f) {
  unsigned int u = __builtin_bit_cast(unsigned int, f);
  u += 0x7FFFu + ((u >> 16) & 1u);   // round-to-nearest-even
  return (unsigned short)(u >> 16);
}

DEVI void load_lds16(const void* g, void* l) {
  __builtin_amdgcn_global_load_lds(
      (__attribute__((address_space(1))) void*)g,
      (__attribute__((address_space(3))) void*)l,
      16, 0, 0);
}

// chunked XCD swizzle (bijective when nwg % 8 == 0)
DEVI int xcd_swz(int bid, int chunk) { return (bid & 7) * chunk + (bid >> 3); }

// ---------------- fused fp32 -> bf16 bulk convert (6 segments, 1 launch) ----------------
struct CvtArgs {
  const float* src[6];
  unsigned short* dst[6];
  int cum[6];
};

__global__ __launch_bounds__(256) void cvt_all(CvtArgs a, int total4) {
  int i = blockIdx.x * 256 + threadIdx.x;
  if (i >= total4) return;
  int s = 0;
#pragma unroll
  for (int k = 1; k < 6; ++k) s += (i >= a.cum[k]);
  const int j = i - a.cum[s];
  const f32x4 v = __builtin_nontemporal_load((const f32x4*)a.src[s] + j);
  ushort4 o;
  o.x = f2bf(v[0]); o.y = f2bf(v[1]); o.z = f2bf(v[2]); o.w = f2bf(v[3]);
  reinterpret_cast<ushort4*>(a.dst[s])[j] = o;
}

// ---------------- shared 128x128xK=1024 GEMM core ----------------
// C = A @ W^T + bias. A: [M,1024] bf16; W: [1024,1024] bf16.
// Epilogues (all coalesced via per-wave LDS transpose):
//   OUT_BF16 && !vt : Q/K layout, off = b*sb + t*st + h*sh + d
//   OUT_BF16 && vt  : V^T layout,  off = b*sb + h*sh + d*sd + t
//   !OUT_BF16       : O fp32,      off = b*sb + t*st + n
template<bool OUT_BF16>
DEVI void gemm_core(const unsigned short* __restrict__ A,
                    const unsigned short* __restrict__ W,
                    const float* __restrict__ bias,
                    void* __restrict__ out,
                    float scale, int log2R,
                    long sb, long st, long sh, long sd,
                    int bx, int by, bool vt)
{
  constexpr int K = 1024;
  __shared__ unsigned short smem[2 * 128 * 64];
  unsigned short* As = smem;
  unsigned short* Bs = smem + 8192;

  const int tid  = threadIdx.x;
  const int wid  = tid >> 6;
  const int lane = tid & 63;
  const int m0 = bx * 128;
  const int n0 = by * 128;
  const int wr = (wid >> 1) * 64;
  const int wc = (wid & 1) * 64;
  const int lg = lane >> 4;
  const int ll = lane & 15;

  f32x4 acc[4][4] = {};

  const char* Ab = (const char*)A + (long)m0 * K * 2;
  const char* Wb = (const char*)W + (long)n0 * K * 2;
  char* AsB = (char*)As;
  char* BsB = (char*)Bs;
  const long rowstride = (long)K * 2;

  for (int kt = 0; kt < K; kt += 64) {
#pragma unroll
    for (int j = 0; j < 4; ++j) {
      const int o    = (wid * 4 + j) * 1024 + lane * 16;
      const int row  = o >> 7;
      const int colb = o & 127;
      load_lds16(Ab + (long)row * rowstride + (long)kt * 2 + colb, AsB + (wid * 4 + j) * 1024);
      load_lds16(Wb + (long)row * rowstride + (long)kt * 2 + colb, BsB + (wid * 4 + j) * 1024);
    }
    __syncthreads();
#pragma unroll
    for (int ks = 0; ks < 2; ++ks) {
      bf16x8 af[4], bfr[4];
#pragma unroll
      for (int i = 0; i < 4; ++i) {
        af[i]  = *(const bf16x8*)&As[(wr + i * 16 + ll) * 64 + ks * 32 + lg * 8];
        bfr[i] = *(const bf16x8*)&Bs[(wc + i * 16 + ll) * 64 + ks * 32 + lg * 8];
      }
#pragma unroll
      for (int i = 0; i < 4; ++i)
#pragma unroll
        for (int j = 0; j < 4; ++j)
          acc[i][j] = __builtin_amdgcn_mfma_f32_16x16x32_bf16(af[i], bfr[j], acc[i][j], 0, 0, 0);
    }
    __syncthreads();
  }

  const int Rmask  = (1 << log2R) - 1;
  const int m_base = m0 + wr;
  const int b   = m_base >> log2R;
  const int tbs = m_base & Rmask;
  const int nn  = n0 + wc;
  float bj[4];
#pragma unroll
  for (int j = 0; j < 4; ++j) bj[j] = bias[nn + j * 16 + ll];

  if (OUT_BF16 && vt) {
    // ---- V epilogue: [b][h][d][t], coalesced t-runs ----
    unsigned short* Tw = smem + wid * 2176;   // 32 x 68
#pragma unroll
    for (int h2 = 0; h2 < 2; ++h2) {
#pragma unroll
      for (int jj = 0; jj < 2; ++jj) {
        const int j = h2 * 2 + jj;
#pragma unroll
        for (int i = 0; i < 4; ++i)
#pragma unroll
          for (int r = 0; r < 4; ++r)
            Tw[(jj * 16 + ll) * 68 + i * 16 + lg * 4 + r] = f2bf((acc[i][j][r] + bj[j]) * scale);
      }
      asm volatile("s_waitcnt lgkmcnt(0)" ::: "memory");
#pragma unroll
      for (int k = 0; k < 8; ++k) {
        const int dloc = k * 4 + lg;
        const int t4   = ll * 4;
        const ushort4 vv = *(const ushort4*)&Tw[dloc * 68 + t4];
        const int n = nn + h2 * 32 + dloc;
        const int h = n >> 6, dd = n & 63;
        *(ushort4*)((unsigned short*)out + (long)b * sb + (long)h * sh + (long)dd * sd + tbs + t4) = vv;
      }
      if (h2 == 0) asm volatile("s_waitcnt lgkmcnt(0)" ::: "memory");
    }
    return;
  }

  if (OUT_BF16) {
    // ---- Q/K epilogue: [b][h][t][d], coalesced d-runs via LDS transpose ----
    const int h = nn >> 6;
    unsigned short* ob = (unsigned short*)out + (long)b * sb + (long)h * sh;
    unsigned short* Tw = smem + wid * 2176;   // 32 x 68
#pragma unroll
    for (int p = 0; p < 2; ++p) {
#pragma unroll
      for (int i2 = 0; i2 < 2; ++i2) {
        const int i = p * 2 + i2;
#pragma unroll
        for (int j = 0; j < 4; ++j)
#pragma unroll
          for (int r = 0; r < 4; ++r)
            Tw[(i2 * 16 + lg * 4 + r) * 68 + j * 16 + ll] = f2bf((acc[i][j][r] + bj[j]) * scale);
      }
      asm volatile("s_waitcnt lgkmcnt(0)" ::: "memory");
#pragma unroll
      for (int k = 0; k < 8; ++k) {
        const int t_loc = k * 4 + lg;
        const int d4    = ll * 4;
        const ushort4 vv = *(const ushort4*)&Tw[t_loc * 68 + d4];
        *(ushort4*)(ob + (long)(tbs + p * 32 + t_loc) * st + d4) = vv;
      }
      if (p == 0) asm volatile("s_waitcnt lgkmcnt(0)" ::: "memory");
    }
    return;
  }

  // ---- O epilogue (fp32): coalesced float2 runs ----
  {
    float* ob = (float*)out + (long)b * sb + nn;
    float* TwF = (float*)smem + wid * 1056;   // 16 x 66
#pragma unroll
    for (int i = 0; i < 4; ++i) {
#pragma unroll
      for (int j = 0; j < 4; ++j)
#pragma unroll
        for (int r = 0; r < 4; ++r)
          TwF[(lg * 4 + r) * 66 + j * 16 + ll] = acc[i][j][r] + bj[j];
      asm volatile("s_waitcnt lgkmcnt(0)" ::: "memory");
#pragma unroll
      for (int k = 0; k < 8; ++k) {
        const int t_loc = k * 2 + (lane >> 5);
        const int c2    = (lane & 31) * 2;
        const float2 v = *(const float2*)&TwF[t_loc * 66 + c2];
        *(float2*)(ob + (long)(tbs + i * 16 + t_loc) * st + c2) = v;
      }
      if (i < 3) asm volatile("s_waitcnt lgkmcnt(0)" ::: "memory");
    }
  }
}

struct GemmDesc {
  const unsigned short* A;
  const unsigned short* W;
  const float* bias;
  unsigned short* out;
  float scale;
  int log2R;
  long sb, st, sh, sd;
};

// fused Q/K/V projections, flat grid 1280 with XCD swizzle
__global__ __launch_bounds__(256) void gemm_qkv(GemmDesc d0, GemmDesc d1, GemmDesc d2) {
  int bid = xcd_swz(blockIdx.x, 160);
  const GemmDesc* d;
  bool vt = false;
  if (bid < 256)      { d = &d0; }
  else if (bid < 768) { d = &d1; bid -= 256; }
  else                { d = &d2; bid -= 768; vt = true; }
  gemm_core<true>(d->A, d->W, d->bias, d->out, d->scale, d->log2R,
                  d->sb, d->st, d->sh, d->sd, bid >> 3, bid & 7, vt);
}

// output projection (fp32 out), flat grid 256 with XCD swizzle
__global__ __launch_bounds__(256) void gemm_o(
    const unsigned short* __restrict__ A,
    const unsigned short* __restrict__ W,
    const float* __restrict__ bias,
    float* __restrict__ out,
    long sb, long st, long sh, long sd)
{
  const int bid = xcd_swz(blockIdx.x, 32);
  gemm_core<false>(A, W, bias, out, 1.0f, 10, sb, st, sh, sd, bid >> 3, bid & 7, false);
}

// ---------------- fused flash attention: gload_lds DOUBLE-BUFFER + counted vmcnt ----------------
// Qb: [B*H, T, 64] bf16 (pre-scaled 1/8); Kb: [B*H, S, 64]; Vt: [B*H, 64, S]
// bias fp32 [B*H,T,S]; Ob: [B*H, T, 64] bf16
// 512 threads = 8 waves, 16 Q-rows/wave -> 128 rows/block, 512 blocks.
// R14 failed via reg-staging VGPR bloat; global_load_lds staging has ZERO register
// cost. Pad is incompatible with gload_lds (m104) -> T21: linear [64][64] LDS +
// XOR-swizzled SOURCE address (cb ^= (row&7)<<4) + same swizzle on ds_reads
// (bank-verified: 2 lanes/bank = free). Chunk sc+1's staging is issued at the top
// of chunk sc and waited with COUNTED vmcnt(6) at the top of chunk sc+1 (the 2
// oldest VMEM in the per-wave queue are always last iteration's staging, so this
// iteration's 6 new loads' internal order is irrelevant). No vmcnt(0) drain
// anywhere in the loop -> staging AND bias latency hide under a full chunk.
__global__ __launch_bounds__(512, 4) void attn_fused(
    const unsigned short* __restrict__ Qb,
    const unsigned short* __restrict__ Kb,
    const unsigned short* __restrict__ Vt,
    const float* __restrict__ bias,
    unsigned short* __restrict__ Ob)
{
  constexpr int T = 1024, S = 2048, NC = S / 64;
  __shared__ unsigned short Ks[2][64 * 64];   // linear [s][d], 8 KB per buf
  __shared__ unsigned short Vs[2][64 * 64];   // linear [d][s], 8 KB per buf
  __shared__ unsigned short Ps[8][16 * 72];   // per-wave P [t 16][s 64] +8 pad

  const int tid = threadIdx.x;
  const int w = tid >> 6, lane = tid & 63;
  const int lg = lane >> 4, ll = lane & 15;

  const int wg = xcd_swz(blockIdx.x, 64);    // 8 consecutive tiles of a bh per XCD
  const int bh = wg >> 3;
  const int tt = wg & 7;
  const int trow = tt * 128 + w * 16;        // this wave's 16 Q-rows

  // Q fragments (B-operand: col t = ll, k = d)
  bf16x8 qf[2];
#pragma unroll
  for (int ks = 0; ks < 2; ++ks)
    qf[ks] = *(const bf16x8*)(Qb + ((long)bh * T + trow + ll) * 64 + ks * 32 + lg * 8);

  f32x4 acc[4] = {};
  float m_run = -1e30f, l_run = 0.0f;

  const char* Kg = (const char*)(Kb + (long)bh * S * 64);
  const char* Vg = (const char*)(Vt + (long)bh * 64 * S);
  const float* bias_row = bias + ((long)bh * T + trow + ll) * S + lg * 4;
  unsigned short* Pw = &Ps[w][0];

  // staging geometry: thread covers row = tid>>3 (0..63), 16B at swizzled col
  const int srow = tid >> 3;
  const int scb  = ((tid & 7) * 16) ^ ((srow & 7) << 4);   // pre-swizzled source col-byte
  // wave-uniform LDS dest bases (gload_lds dest = base + lane*16)
  char* ksW = (char*)&Ks[0][0] + w * 1024;
  char* vsW = (char*)&Vs[0][0] + w * 1024;

  auto stageK = [&](int sc, int buf) {
    load_lds16(Kg + (long)(sc * 64 + srow) * 128 + scb, ksW + buf * 8192);
  };
  auto stageV = [&](int sc, int buf) {
    load_lds16(Vg + (long)srow * (S * 2) + sc * 128 + scb, vsW + buf * 8192);
  };

  // prologue: stage chunk 0 -> buf 0 (2 VMEM outstanding entering the loop)
  stageK(0, 0);
  stageV(0, 0);

  for (int sc = 0; sc < NC; ++sc) {
    const int cur = sc & 1;
    // 1) prefetch chunk sc+1 -> buf cur^1 (clamped on last iter: uniform VMEM count)
    const int nsc = (sc + 1 < NC) ? sc + 1 : 0;
    stageK(nsc, cur ^ 1);
    stageV(nsc, cur ^ 1);

    // 2) bias for this chunk (4 f32x4, nontemporal)
    const float* bp = bias_row + sc * 64;
    f32x4 b4[4];
#pragma unroll
    for (int sf = 0; sf < 4; ++sf)
      b4[sf] = __builtin_nontemporal_load((const f32x4*)(bp + sf * 16));

    // 3) counted wait: oldest 2 VMEM = chunk sc's staging (issued last iteration)
    __builtin_amdgcn_sched_barrier(0);
    asm volatile("s_waitcnt vmcnt(6)" ::: "memory");
    __builtin_amdgcn_s_barrier();
    __builtin_amdgcn_sched_barrier(0);

    // 4) swapped QK^T from buf cur (swizzled reads): lane holds (s=sf*16+lg*4+r, t=trow+ll)
    f32x4 sv[4] = {};
    __builtin_amdgcn_s_setprio(1);
#pragma unroll
    for (int ks = 0; ks < 2; ++ks) {
#pragma unroll
      for (int sf = 0; sf < 4; ++sf) {
        const int r = sf * 16 + ll;
        const int c = (ks * 64 + lg * 16) ^ ((r & 7) << 4);
        const bf16x8 kf = *(const bf16x8*)((const char*)&Ks[cur][0] + r * 128 + c);
        sv[sf] = __builtin_amdgcn_mfma_f32_16x16x32_bf16(kf, qf[ks], sv[sf], 0, 0, 0);
      }
    }
    __builtin_amdgcn_s_setprio(0);

#pragma unroll
    for (int sf = 0; sf < 4; ++sf) {
      sv[sf][0] += b4[sf][0]; sv[sf][1] += b4[sf][1];
      sv[sf][2] += b4[sf][2]; sv[sf][3] += b4[sf][3];
    }

    // 5) online softmax over s (16 in-reg + 2 shuffles)
    float cm = sv[0][0];
#pragma unroll
    for (int sf = 0; sf < 4; ++sf)
#pragma unroll
      for (int r = 0; r < 4; ++r) cm = fmaxf(cm, sv[sf][r]);
    cm = fmaxf(cm, __shfl_xor(cm, 16));
    cm = fmaxf(cm, __shfl_xor(cm, 32));

    const float mnew = fmaxf(m_run, cm);
    const float alpha = __expf(m_run - mnew);
    float ps = 0.0f;
#pragma unroll
    for (int sf = 0; sf < 4; ++sf)
#pragma unroll
      for (int r = 0; r < 4; ++r) {
        const float p = __expf(sv[sf][r] - mnew);
        sv[sf][r] = p;
        ps += p;
      }
    ps += __shfl_xor(ps, 16);
    ps += __shfl_xor(ps, 32);
    l_run = l_run * alpha + ps;
    m_run = mnew;

    float ar[4];
#pragma unroll
    for (int r = 0; r < 4; ++r) ar[r] = __shfl(alpha, lg * 4 + r);
#pragma unroll
    for (int df = 0; df < 4; ++df)
#pragma unroll
      for (int r = 0; r < 4; ++r) acc[df][r] *= ar[r];

    // 6) write P^T frags -> Ps[w] [t][s] (4x ds_write_b64, wave-private, padded)
#pragma unroll
    for (int sf = 0; sf < 4; ++sf) {
      ushort4 pw;
      pw.x = f2bf(sv[sf][0]); pw.y = f2bf(sv[sf][1]);
      pw.z = f2bf(sv[sf][2]); pw.w = f2bf(sv[sf][3]);
      *(ushort4*)&Pw[ll * 72 + sf * 16 + lg * 4] = pw;
    }
    asm volatile("s_waitcnt lgkmcnt(0)" ::: "memory");
    __builtin_amdgcn_sched_barrier(0);

    // 7) PV from buf cur (swizzled V reads): acc[t][d] += P[t][s] * V[s][d]
    __builtin_amdgcn_s_setprio(1);
#pragma unroll
    for (int ks = 0; ks < 2; ++ks) {
      bf16x8 pa = *(const bf16x8*)((const char*)Pw + ll * 144 + ks * 64 + lg * 16);
#pragma unroll
      for (int df = 0; df < 4; ++df) {
        const int d = df * 16 + ll;
        const int c = (ks * 64 + lg * 16) ^ ((d & 7) << 4);
        const bf16x8 vf = *(const bf16x8*)((const char*)&Vs[cur][0] + d * 128 + c);
        acc[df] = __builtin_amdgcn_mfma_f32_16x16x32_bf16(pa, vf, acc[df], 0, 0, 0);
      }
    }
    __builtin_amdgcn_s_setprio(0);

    // 8) end barrier: all reads of buf cur done before next iter's gload_lds
    //    overwrites it (plain barrier; in-wave ds_reads already retired by MFMAs)
    __builtin_amdgcn_sched_barrier(0);
    __builtin_amdgcn_s_barrier();
    __builtin_amdgcn_sched_barrier(0);
  }

  // epilogue: normalize and store
  const float inv = 1.0f / l_run;
  float ir[4];
#pragma unroll
  for (int r = 0; r < 4; ++r) ir[r] = __shfl(inv, lg * 4 + r);
#pragma unroll
  for (int df = 0; df < 4; ++df)
#pragma unroll
    for (int r = 0; r < 4; ++r) {
      const long oo = ((long)bh * T + trow + lg * 4 + r) * 64 + df * 16 + ll;
      Ob[oo] = f2bf(acc[df][r] * ir[r]);
    }
}

// ---------------- host launch ----------------
extern "C" void kernel_launch(void* const* d_in, const int* in_sizes, int n_in,
                              void* d_out, int out_size, void* d_ws, size_t ws_size,
                              hipStream_t stream) {
  constexpr int B = 4, T = 1024, S = 2048, E = 1024;
  const float* hs   = (const float*)d_in[0];
  const float* kv   = (const float*)d_in[1];
  const float* bias = (const float*)d_in[2];
  const float* Wq   = (const float*)d_in[3];
  const float* bq   = (const float*)d_in[4];
  const float* Wk   = (const float*)d_in[5];
  const float* bk   = (const float*)d_in[6];
  const float* Wv   = (const float*)d_in[7];
  const float* bv   = (const float*)d_in[8];
  const float* Wo   = (const float*)d_in[9];
  const float* bo   = (const float*)d_in[10];

  char* ws = (char*)d_ws;
  const size_t MB = 1024 * 1024;
  unsigned short* hs_bf = (unsigned short*)(ws);
  unsigned short* kv_bf = (unsigned short*)(ws + 8 * MB);
  unsigned short* wq_bf = (unsigned short*)(ws + 24 * MB);
  unsigned short* wk_bf = (unsigned short*)(ws + 26 * MB);
  unsigned short* wv_bf = (unsigned short*)(ws + 28 * MB);
  unsigned short* wo_bf = (unsigned short*)(ws + 30 * MB);
  unsigned short* q_buf = (unsigned short*)(ws + 32 * MB);
  unsigned short* k_buf = (unsigned short*)(ws + 40 * MB);
  unsigned short* v_buf = (unsigned short*)(ws + 56 * MB);
  unsigned short* a_buf = (unsigned short*)(ws + 72 * MB);

  CvtArgs ca;
  ca.src[0] = hs;  ca.dst[0] = hs_bf;
  ca.src[1] = kv;  ca.dst[1] = kv_bf;
  ca.src[2] = Wq;  ca.dst[2] = wq_bf;
  ca.src[3] = Wk;  ca.dst[3] = wk_bf;
  ca.src[4] = Wv;  ca.dst[4] = wv_bf;
  ca.src[5] = Wo;  ca.dst[5] = wo_bf;
  const int n4_hs = B * T * E / 4, n4_kv = B * S * E / 4, n4_w = E * E / 4;
  ca.cum[0] = 0;
  ca.cum[1] = n4_hs;
  ca.cum[2] = n4_hs + n4_kv;
  ca.cum[3] = n4_hs + n4_kv + n4_w;
  ca.cum[4] = n4_hs + n4_kv + 2 * n4_w;
  ca.cum[5] = n4_hs + n4_kv + 3 * n4_w;
  const int total4 = n4_hs + n4_kv + 4 * n4_w;
  cvt_all<<<dim3((total4 + 255) / 256), dim3(256), 0, stream>>>(ca, total4);

  GemmDesc dq{hs_bf, wq_bf, bq, q_buf, 0.125f, 10,
              (long)T * E, 64L, (long)T * 64, 1L};
  GemmDesc dk{kv_bf, wk_bf, bk, k_buf, 1.0f, 11,
              (long)S * E, 64L, (long)S * 64, 1L};
  GemmDesc dv{kv_bf, wv_bf, bv, v_buf, 1.0f, 11,
              (long)S * E, 1L, (long)S * 64, (long)S};
  gemm_qkv<<<dim3(1280), 256, 0, stream>>>(dq, dk, dv);

  attn_fused<<<dim3(512), dim3(512), 0, stream>>>(q_buf, k_buf, v_buf, bias, a_buf);

  gemm_o<<<dim3(256), 256, 0, stream>>>(
      a_buf, wo_bf, bo, (float*)d_out,
      (long)T * E, (long)E, 64L, 1L);
}

// Round 19
// 273.634 us; speedup vs baseline: 1.0000x; 1.0000x over previous
//
#include <hip/hip_runtime.h>

#define DEVI __device__ __forceinline__

typedef __attribute__((ext_vector_type(4))) float f32x4;
typedef __attribute__((ext_vector_type(8))) short bf16x8;

DEVI unsigned short f2bf(float f) {
  unsigned int u = __builtin_bit_cast(unsigned int, f);
  u += 0x7FFFu + ((u >> 16) & 1u);   // round-to-nearest-even
  return (unsigned short)(u >> 16);
}

DEVI void load_lds16(const void* g, void* l) {
  __builtin_amdgcn_global_load_lds(
      (__attribute__((address_space(1))) void*)g,
      (__attribute__((address_space(3))) void*)l,
      16, 0, 0);
}

// chunked XCD swizzle (bijective when nwg % 8 == 0)
DEVI int xcd_swz(int bid, int chunk) { return (bid & 7) * chunk + (bid >> 3); }

// ---------------- fused fp32 -> bf16 bulk convert (6 segments, 1 launch) ----------------
struct CvtArgs {
  const float* src[6];
  unsigned short* dst[6];
  int cum[6];
};

__global__ __launch_bounds__(256) void cvt_all(CvtArgs a, int total4) {
  int i = blockIdx.x * 256 + threadIdx.x;
  if (i >= total4) return;
  int s = 0;
#pragma unroll
  for (int k = 1; k < 6; ++k) s += (i >= a.cum[k]);
  const int j = i - a.cum[s];
  const f32x4 v = __builtin_nontemporal_load((const f32x4*)a.src[s] + j);
  ushort4 o;
  o.x = f2bf(v[0]); o.y = f2bf(v[1]); o.z = f2bf(v[2]); o.w = f2bf(v[3]);
  reinterpret_cast<ushort4*>(a.dst[s])[j] = o;
}

// ---------------- shared 128x128xK=1024 GEMM core ----------------
// C = A @ W^T + bias. A: [M,1024] bf16; W: [1024,1024] bf16.
// Epilogues (all coalesced via per-wave LDS transpose):
//   OUT_BF16 && !vt : Q/K layout, off = b*sb + t*st + h*sh + d
//   OUT_BF16 && vt  : V^T layout,  off = b*sb + h*sh + d*sd + t
//   !OUT_BF16       : O fp32,      off = b*sb + t*st + n
template<bool OUT_BF16>
DEVI void gemm_core(const unsigned short* __restrict__ A,
                    const unsigned short* __restrict__ W,
                    const float* __restrict__ bias,
                    void* __restrict__ out,
                    float scale, int log2R,
                    long sb, long st, long sh, long sd,
                    int bx, int by, bool vt)
{
  constexpr int K = 1024;
  __shared__ unsigned short smem[2 * 128 * 64];
  unsigned short* As = smem;
  unsigned short* Bs = smem + 8192;

  const int tid  = threadIdx.x;
  const int wid  = tid >> 6;
  const int lane = tid & 63;
  const int m0 = bx * 128;
  const int n0 = by * 128;
  const int wr = (wid >> 1) * 64;
  const int wc = (wid & 1) * 64;
  const int lg = lane >> 4;
  const int ll = lane & 15;

  f32x4 acc[4][4] = {};

  const char* Ab = (const char*)A + (long)m0 * K * 2;
  const char* Wb = (const char*)W + (long)n0 * K * 2;
  char* AsB = (char*)As;
  char* BsB = (char*)Bs;
  const long rowstride = (long)K * 2;

  for (int kt = 0; kt < K; kt += 64) {
#pragma unroll
    for (int j = 0; j < 4; ++j) {
      const int o    = (wid * 4 + j) * 1024 + lane * 16;
      const int row  = o >> 7;
      const int colb = o & 127;
      load_lds16(Ab + (long)row * rowstride + (long)kt * 2 + colb, AsB + (wid * 4 + j) * 1024);
      load_lds16(Wb + (long)row * rowstride + (long)kt * 2 + colb, BsB + (wid * 4 + j) * 1024);
    }
    __syncthreads();
#pragma unroll
    for (int ks = 0; ks < 2; ++ks) {
      bf16x8 af[4], bfr[4];
#pragma unroll
      for (int i = 0; i < 4; ++i) {
        af[i]  = *(const bf16x8*)&As[(wr + i * 16 + ll) * 64 + ks * 32 + lg * 8];
        bfr[i] = *(const bf16x8*)&Bs[(wc + i * 16 + ll) * 64 + ks * 32 + lg * 8];
      }
#pragma unroll
      for (int i = 0; i < 4; ++i)
#pragma unroll
        for (int j = 0; j < 4; ++j)
          acc[i][j] = __builtin_amdgcn_mfma_f32_16x16x32_bf16(af[i], bfr[j], acc[i][j], 0, 0, 0);
    }
    __syncthreads();
  }

  const int Rmask  = (1 << log2R) - 1;
  const int m_base = m0 + wr;
  const int b   = m_base >> log2R;
  const int tbs = m_base & Rmask;
  const int nn  = n0 + wc;
  float bj[4];
#pragma unroll
  for (int j = 0; j < 4; ++j) bj[j] = bias[nn + j * 16 + ll];

  if (OUT_BF16 && vt) {
    // ---- V epilogue: [b][h][d][t], coalesced t-runs ----
    unsigned short* Tw = smem + wid * 2176;   // 32 x 68
#pragma unroll
    for (int h2 = 0; h2 < 2; ++h2) {
#pragma unroll
      for (int jj = 0; jj < 2; ++jj) {
        const int j = h2 * 2 + jj;
#pragma unroll
        for (int i = 0; i < 4; ++i)
#pragma unroll
          for (int r = 0; r < 4; ++r)
            Tw[(jj * 16 + ll) * 68 + i * 16 + lg * 4 + r] = f2bf((acc[i][j][r] + bj[j]) * scale);
      }
      asm volatile("s_waitcnt lgkmcnt(0)" ::: "memory");
#pragma unroll
      for (int k = 0; k < 8; ++k) {
        const int dloc = k * 4 + lg;
        const int t4   = ll * 4;
        const ushort4 vv = *(const ushort4*)&Tw[dloc * 68 + t4];
        const int n = nn + h2 * 32 + dloc;
        const int h = n >> 6, dd = n & 63;
        *(ushort4*)((unsigned short*)out + (long)b * sb + (long)h * sh + (long)dd * sd + tbs + t4) = vv;
      }
      if (h2 == 0) asm volatile("s_waitcnt lgkmcnt(0)" ::: "memory");
    }
    return;
  }

  if (OUT_BF16) {
    // ---- Q/K epilogue: [b][h][t][d], coalesced d-runs via LDS transpose ----
    const int h = nn >> 6;
    unsigned short* ob = (unsigned short*)out + (long)b * sb + (long)h * sh;
    unsigned short* Tw = smem + wid * 2176;   // 32 x 68
#pragma unroll
    for (int p = 0; p < 2; ++p) {
#pragma unroll
      for (int i2 = 0; i2 < 2; ++i2) {
        const int i = p * 2 + i2;
#pragma unroll
        for (int j = 0; j < 4; ++j)
#pragma unroll
          for (int r = 0; r < 4; ++r)
            Tw[(i2 * 16 + lg * 4 + r) * 68 + j * 16 + ll] = f2bf((acc[i][j][r] + bj[j]) * scale);
      }
      asm volatile("s_waitcnt lgkmcnt(0)" ::: "memory");
#pragma unroll
      for (int k = 0; k < 8; ++k) {
        const int t_loc = k * 4 + lg;
        const int d4    = ll * 4;
        const ushort4 vv = *(const ushort4*)&Tw[t_loc * 68 + d4];
        *(ushort4*)(ob + (long)(tbs + p * 32 + t_loc) * st + d4) = vv;
      }
      if (p == 0) asm volatile("s_waitcnt lgkmcnt(0)" ::: "memory");
    }
    return;
  }

  // ---- O epilogue (fp32): coalesced float2 runs ----
  {
    float* ob = (float*)out + (long)b * sb + nn;
    float* TwF = (float*)smem + wid * 1056;   // 16 x 66
#pragma unroll
    for (int i = 0; i < 4; ++i) {
#pragma unroll
      for (int j = 0; j < 4; ++j)
#pragma unroll
        for (int r = 0; r < 4; ++r)
          TwF[(lg * 4 + r) * 66 + j * 16 + ll] = acc[i][j][r] + bj[j];
      asm volatile("s_waitcnt lgkmcnt(0)" ::: "memory");
#pragma unroll
      for (int k = 0; k < 8; ++k) {
        const int t_loc = k * 2 + (lane >> 5);
        const int c2    = (lane & 31) * 2;
        const float2 v = *(const float2*)&TwF[t_loc * 66 + c2];
        *(float2*)(ob + (long)(tbs + i * 16 + t_loc) * st + c2) = v;
      }
      if (i < 3) asm volatile("s_waitcnt lgkmcnt(0)" ::: "memory");
    }
  }
}

struct GemmDesc {
  const unsigned short* A;
  const unsigned short* W;
  const float* bias;
  unsigned short* out;
  float scale;
  int log2R;
  long sb, st, sh, sd;
};

// fused Q/K/V projections, flat grid 1280 with XCD swizzle
__global__ __launch_bounds__(256) void gemm_qkv(GemmDesc d0, GemmDesc d1, GemmDesc d2) {
  int bid = xcd_swz(blockIdx.x, 160);
  const GemmDesc* d;
  bool vt = false;
  if (bid < 256)      { d = &d0; }
  else if (bid < 768) { d = &d1; bid -= 256; }
  else                { d = &d2; bid -= 768; vt = true; }
  gemm_core<true>(d->A, d->W, d->bias, d->out, d->scale, d->log2R,
                  d->sb, d->st, d->sh, d->sd, bid >> 3, bid & 7, vt);
}

// output projection (fp32 out), flat grid 256 with XCD swizzle
__global__ __launch_bounds__(256) void gemm_o(
    const unsigned short* __restrict__ A,
    const unsigned short* __restrict__ W,
    const float* __restrict__ bias,
    float* __restrict__ out,
    long sb, long st, long sh, long sd)
{
  const int bid = xcd_swz(blockIdx.x, 32);
  gemm_core<false>(A, W, bias, out, 1.0f, 10, sb, st, sh, sd, bid >> 3, bid & 7, false);
}

// ---------------- fused flash attention, swapped-QK^T, 8-wave blocks ----------------
// Qb: [B*H, T, 64] bf16 (pre-scaled 1/8); Kb: [B*H, S, 64]; Vt: [B*H, 64, S]
// bias fp32 [B*H,T,S]; Ob: [B*H, T, 64] bf16
// R9 structure (best measured) + T5 s_setprio around the MFMA clusters.
__global__ __launch_bounds__(512, 4) void attn_fused(
    const unsigned short* __restrict__ Qb,
    const unsigned short* __restrict__ Kb,
    const unsigned short* __restrict__ Vt,
    const float* __restrict__ bias,
    unsigned short* __restrict__ Ob)
{
  constexpr int T = 1024, S = 2048, NC = S / 64;
  __shared__ unsigned short Ks[64 * 72];      // [s][d] +8 pad
  __shared__ unsigned short Vs[64 * 72];      // [d][s] +8 pad
  __shared__ unsigned short Ps[8][16 * 72];   // per-wave P [t 16][s 64] +8 pad

  const int tid = threadIdx.x;
  const int w = tid >> 6, lane = tid & 63;
  const int lg = lane >> 4, ll = lane & 15;

  const int wg = xcd_swz(blockIdx.x, 64);    // 8 consecutive tiles of a bh per XCD
  const int bh = wg >> 3;
  const int tt = wg & 7;
  const int trow = tt * 128 + w * 16;        // this wave's 16 Q-rows

  // Q fragments (B-operand: col t = ll, k = d)
  bf16x8 qf[2];
#pragma unroll
  for (int ks = 0; ks < 2; ++ks)
    qf[ks] = *(const bf16x8*)(Qb + ((long)bh * T + trow + ll) * 64 + ks * 32 + lg * 8);

  f32x4 acc[4] = {};
  float m_run = -1e30f, l_run = 0.0f;

  const char* Kg = (const char*)(Kb + (long)bh * S * 64);
  const char* Vg = (const char*)(Vt + (long)bh * 64 * S);
  const float* bias_row = bias + ((long)bh * T + trow + ll) * S + lg * 4;
  unsigned short* Pw = &Ps[w][0];

  // staging addresses: 512 threads x (16B K + 16B V) per chunk
  const int srow = tid >> 3;          // 0..63
  const int scolb = (tid & 7) * 16;   // 0..112

  for (int sc = 0; sc < NC; ++sc) {
    // 1) issue bias loads first (independent; in flight across staging + barrier + QK^T)
    const float* bp = bias_row + sc * 64;
    f32x4 b4[4];
#pragma unroll
    for (int sf = 0; sf < 4; ++sf)
      b4[sf] = __builtin_nontemporal_load((const f32x4*)(bp + sf * 16));

    // 2) stage K [64 s][64 d] and V^T [64 d][64 s] into padded LDS
    {
      const uint4 kd = *(const uint4*)(Kg + (long)(sc * 64 + srow) * 128 + scolb);
      *(uint4*)((char*)&Ks[0] + srow * 144 + scolb) = kd;
      const uint4 vd = *(const uint4*)(Vg + (long)srow * (S * 2) + sc * 128 + scolb);
      *(uint4*)((char*)&Vs[0] + srow * 144 + scolb) = vd;
    }
    __syncthreads();

    // 3) swapped QK^T: lane holds (s = sf*16 + lg*4 + r, t = trow + ll)
    f32x4 sv[4] = {};
    __builtin_amdgcn_s_setprio(1);
#pragma unroll
    for (int ks = 0; ks < 2; ++ks) {
      bf16x8 kf[4];
#pragma unroll
      for (int sf = 0; sf < 4; ++sf)
        kf[sf] = *(const bf16x8*)((const char*)&Ks[0] + (sf * 16 + ll) * 144 + (ks * 32 + lg * 8) * 2);
#pragma unroll
      for (int sf = 0; sf < 4; ++sf)
        sv[sf] = __builtin_amdgcn_mfma_f32_16x16x32_bf16(kf[sf], qf[ks], sv[sf], 0, 0, 0);
    }
    __builtin_amdgcn_s_setprio(0);

#pragma unroll
    for (int sf = 0; sf < 4; ++sf) {
      sv[sf][0] += b4[sf][0]; sv[sf][1] += b4[sf][1];
      sv[sf][2] += b4[sf][2]; sv[sf][3] += b4[sf][3];
    }

    // 4) online softmax over s (16 in-reg + 2 shuffles)
    float cm = sv[0][0];
#pragma unroll
    for (int sf = 0; sf < 4; ++sf)
#pragma unroll
      for (int r = 0; r < 4; ++r) cm = fmaxf(cm, sv[sf][r]);
    cm = fmaxf(cm, __shfl_xor(cm, 16));
    cm = fmaxf(cm, __shfl_xor(cm, 32));

    const float mnew = fmaxf(m_run, cm);
    const float alpha = __expf(m_run - mnew);
    float ps = 0.0f;
#pragma unroll
    for (int sf = 0; sf < 4; ++sf)
#pragma unroll
      for (int r = 0; r < 4; ++r) {
        const float p = __expf(sv[sf][r] - mnew);
        sv[sf][r] = p;
        ps += p;
      }
    ps += __shfl_xor(ps, 16);
    ps += __shfl_xor(ps, 32);
    l_run = l_run * alpha + ps;
    m_run = mnew;

    float ar[4];
#pragma unroll
    for (int r = 0; r < 4; ++r) ar[r] = __shfl(alpha, lg * 4 + r);
#pragma unroll
    for (int df = 0; df < 4; ++df)
#pragma unroll
      for (int r = 0; r < 4; ++r) acc[df][r] *= ar[r];

    // 5) write P^T frags -> Ps[w] [t][s] (4x ds_write_b64)
#pragma unroll
    for (int sf = 0; sf < 4; ++sf) {
      ushort4 pw;
      pw.x = f2bf(sv[sf][0]); pw.y = f2bf(sv[sf][1]);
      pw.z = f2bf(sv[sf][2]); pw.w = f2bf(sv[sf][3]);
      *(ushort4*)&Pw[ll * 72 + sf * 16 + lg * 4] = pw;
    }
    asm volatile("s_waitcnt lgkmcnt(0)" ::: "memory");
    __builtin_amdgcn_sched_barrier(0);

    // 6) PV: acc[t][d] += P[t][s] * V[s][d]
    __builtin_amdgcn_s_setprio(1);
#pragma unroll
    for (int ks = 0; ks < 2; ++ks) {
      bf16x8 pa = *(const bf16x8*)((const char*)Pw + ll * 144 + ks * 64 + lg * 16);
      bf16x8 vf[4];
#pragma unroll
      for (int df = 0; df < 4; ++df)
        vf[df] = *(const bf16x8*)((const char*)&Vs[0] + (df * 16 + ll) * 144 + (ks * 32 + lg * 8) * 2);
#pragma unroll
      for (int df = 0; df < 4; ++df)
        acc[df] = __builtin_amdgcn_mfma_f32_16x16x32_bf16(pa, vf[df], acc[df], 0, 0, 0);
    }
    __builtin_amdgcn_s_setprio(0);
    __syncthreads();
  }

  // epilogue: normalize and store
  const float inv = 1.0f / l_run;
  float ir[4];
#pragma unroll
  for (int r = 0; r < 4; ++r) ir[r] = __shfl(inv, lg * 4 + r);
#pragma unroll
  for (int df = 0; df < 4; ++df)
#pragma unroll
    for (int r = 0; r < 4; ++r) {
      const long oo = ((long)bh * T + trow + lg * 4 + r) * 64 + df * 16 + ll;
      Ob[oo] = f2bf(acc[df][r] * ir[r]);
    }
}

// ---------------- host launch ----------------
extern "C" void kernel_launch(void* const* d_in, const int* in_sizes, int n_in,
                              void* d_out, int out_size, void* d_ws, size_t ws_size,
                              hipStream_t stream) {
  constexpr int B = 4, T = 1024, S = 2048, E = 1024;
  const float* hs   = (const float*)d_in[0];
  const float* kv   = (const float*)d_in[1];
  const float* bias = (const float*)d_in[2];
  const float* Wq   = (const float*)d_in[3];
  const float* bq   = (const float*)d_in[4];
  const float* Wk   = (const float*)d_in[5];
  const float* bk   = (const float*)d_in[6];
  const float* Wv   = (const float*)d_in[7];
  const float* bv   = (const float*)d_in[8];
  const float* Wo   = (const float*)d_in[9];
  const float* bo   = (const float*)d_in[10];

  char* ws = (char*)d_ws;
  const size_t MB = 1024 * 1024;
  unsigned short* hs_bf = (unsigned short*)(ws);
  unsigned short* kv_bf = (unsigned short*)(ws + 8 * MB);
  unsigned short* wq_bf = (unsigned short*)(ws + 24 * MB);
  unsigned short* wk_bf = (unsigned short*)(ws + 26 * MB);
  unsigned short* wv_bf = (unsigned short*)(ws + 28 * MB);
  unsigned short* wo_bf = (unsigned short*)(ws + 30 * MB);
  unsigned short* q_buf = (unsigned short*)(ws + 32 * MB);
  unsigned short* k_buf = (unsigned short*)(ws + 40 * MB);
  unsigned short* v_buf = (unsigned short*)(ws + 56 * MB);
  unsigned short* a_buf = (unsigned short*)(ws + 72 * MB);

  CvtArgs ca;
  ca.src[0] = hs;  ca.dst[0] = hs_bf;
  ca.src[1] = kv;  ca.dst[1] = kv_bf;
  ca.src[2] = Wq;  ca.dst[2] = wq_bf;
  ca.src[3] = Wk;  ca.dst[3] = wk_bf;
  ca.src[4] = Wv;  ca.dst[4] = wv_bf;
  ca.src[5] = Wo;  ca.dst[5] = wo_bf;
  const int n4_hs = B * T * E / 4, n4_kv = B * S * E / 4, n4_w = E * E / 4;
  ca.cum[0] = 0;
  ca.cum[1] = n4_hs;
  ca.cum[2] = n4_hs + n4_kv;
  ca.cum[3] = n4_hs + n4_kv + n4_w;
  ca.cum[4] = n4_hs + n4_kv + 2 * n4_w;
  ca.cum[5] = n4_hs + n4_kv + 3 * n4_w;
  const int total4 = n4_hs + n4_kv + 4 * n4_w;
  cvt_all<<<dim3((total4 + 255) / 256), dim3(256), 0, stream>>>(ca, total4);

  GemmDesc dq{hs_bf, wq_bf, bq, q_buf, 0.125f, 10,
              (long)T * E, 64L, (long)T * 64, 1L};
  GemmDesc dk{kv_bf, wk_bf, bk, k_buf, 1.0f, 11,
              (long)S * E, 64L, (long)S * 64, 1L};
  GemmDesc dv{kv_bf, wv_bf, bv, v_buf, 1.0f, 11,
              (long)S * E, 1L, (long)S * 64, (long)S};
  gemm_qkv<<<dim3(1280), 256, 0, stream>>>(dq, dk, dv);

  attn_fused<<<dim3(512), dim3(512), 0, stream>>>(q_buf, k_buf, v_buf, bias, a_buf);

  gemm_o<<<dim3(256), 256, 0, stream>>>(
      a_buf, wo_bf, bo, (float*)d_out,
      (long)T * E, (long)E, 64L, 1L);
}

// Round 20
// 254.610 us; speedup vs baseline: 1.0747x; 1.0747x over previous
//
#include <hip/hip_runtime.h>

#define DEVI __device__ __forceinline__

typedef __attribute__((ext_vector_type(4))) float f32x4;
typedef __attribute__((ext_vector_type(8))) short bf16x8;

DEVI unsigned short f2bf(float f) {
  unsigned int u = __builtin_bit_cast(unsigned int, f);
  u += 0x7FFFu + ((u >> 16) & 1u);   // round-to-nearest-even
  return (unsigned short)(u >> 16);
}

DEVI void load_lds16(const void* g, void* l) {
  __builtin_amdgcn_global_load_lds(
      (__attribute__((address_space(1))) void*)g,
      (__attribute__((address_space(3))) void*)l,
      16, 0, 0);
}

// chunked XCD swizzle (bijective when nwg % 8 == 0)
DEVI int xcd_swz(int bid, int chunk) { return (bid & 7) * chunk + (bid >> 3); }

// ---------------- fused fp32 -> bf16 bulk convert (6 segments, 1 launch) ----------------
struct CvtArgs {
  const float* src[6];
  unsigned short* dst[6];
  int cum[6];
};

__global__ __launch_bounds__(256) void cvt_all(CvtArgs a, int total4) {
  int i = blockIdx.x * 256 + threadIdx.x;
  if (i >= total4) return;
  int s = 0;
#pragma unroll
  for (int k = 1; k < 6; ++k) s += (i >= a.cum[k]);
  const int j = i - a.cum[s];
  const f32x4 v = __builtin_nontemporal_load((const f32x4*)a.src[s] + j);
  ushort4 o;
  o.x = f2bf(v[0]); o.y = f2bf(v[1]); o.z = f2bf(v[2]); o.w = f2bf(v[3]);
  reinterpret_cast<ushort4*>(a.dst[s])[j] = o;
}

// ---------------- shared 128x128xK=1024 GEMM core, 2-PHASE double-buffer ----------------
// C = A @ W^T + bias. A: [M,1024] bf16; W: [1024,1024] bf16.
// T3 "minimum 2-phase" (guide §5.5): per K-step, issue NEXT tile's global_load_lds
// FIRST, then compute the CURRENT tile, then ONE __syncthreads (full vmcnt drain +
// barrier -- correct by construction, no raw barriers / counted vmcnt -> no race
// surface; the drain is ~free because the loads had a full compute phase in flight).
// BK=32: 2 x (A 8KB + W 8KB) buffers = 32 KB total (unchanged occupancy); 64 B rows
// halve the frag-read bank conflict vs the old 128 B rows (8-way vs 16-way).
// Accumulation order over K identical to the old BK=64/ks loop -> bitwise-same acc.
template<bool OUT_BF16>
DEVI void gemm_core(const unsigned short* __restrict__ A,
                    const unsigned short* __restrict__ W,
                    const float* __restrict__ bias,
                    void* __restrict__ out,
                    float scale, int log2R,
                    long sb, long st, long sh, long sd,
                    int bx, int by, bool vt)
{
  constexpr int K = 1024, NT = K / 32;       // 32 K-tiles of 32
  __shared__ unsigned short smem[2 * 8192];   // 32 KB: 2 bufs x (A 8KB + W 8KB)

  const int tid  = threadIdx.x;
  const int wid  = tid >> 6;
  const int lane = tid & 63;
  const int m0 = bx * 128;
  const int n0 = by * 128;
  const int wr = (wid >> 1) * 64;
  const int wc = (wid & 1) * 64;
  const int lg = lane >> 4;
  const int ll = lane & 15;

  f32x4 acc[4][4] = {};

  const char* Ab = (const char*)A + (long)m0 * K * 2;
  const char* Wb = (const char*)W + (long)n0 * K * 2;
  const long rowstride = (long)K * 2;

  // staging: tile = 128 rows x 32 cols (64 B/row) = 8 KB = 8 chunks of 1 KB.
  // wave w stages chunks {2w,2w+1} of A and of W -> 4 gload_lds/thread-step.
  const int r_off = lane >> 2;          // row within 16-row chunk
  const int cb    = (lane & 3) * 16;    // col-byte 0..48

  auto stage = [&](int tile, int buf) {
    const long ktb = (long)tile * 64;   // byte offset within a row
    char* base = (char*)smem + buf * 16384;
#pragma unroll
    for (int c = 0; c < 2; ++c) {
      const int ch  = 2 * wid + c;      // chunk 0..7
      const int row = ch * 16 + r_off;
      load_lds16(Ab + (long)row * rowstride + ktb + cb, base + ch * 1024);
      load_lds16(Wb + (long)row * rowstride + ktb + cb, base + 8192 + ch * 1024);
    }
  };

  auto compute = [&](int buf) {
    const char* base = (const char*)smem + buf * 16384;
    bf16x8 af[4], bfr[4];
#pragma unroll
    for (int i = 0; i < 4; ++i) {
      af[i]  = *(const bf16x8*)(base + (wr + i * 16 + ll) * 64 + lg * 16);
      bfr[i] = *(const bf16x8*)(base + 8192 + (wc + i * 16 + ll) * 64 + lg * 16);
    }
#pragma unroll
    for (int i = 0; i < 4; ++i)
#pragma unroll
      for (int j = 0; j < 4; ++j)
        acc[i][j] = __builtin_amdgcn_mfma_f32_16x16x32_bf16(af[i], bfr[j], acc[i][j], 0, 0, 0);
  };

  stage(0, 0);
  __syncthreads();
  for (int kt = 0; kt < NT; ++kt) {
    const int cur = kt & 1;
    if (kt + 1 < NT) stage(kt + 1, cur ^ 1);   // issue BEFORE compute: latency hides
    compute(cur);
    __syncthreads();                            // full drain + barrier (race-free)
  }

  const int Rmask  = (1 << log2R) - 1;
  const int m_base = m0 + wr;
  const int b   = m_base >> log2R;
  const int tbs = m_base & Rmask;
  const int nn  = n0 + wc;
  float bj[4];
#pragma unroll
  for (int j = 0; j < 4; ++j) bj[j] = bias[nn + j * 16 + ll];

  if (OUT_BF16 && vt) {
    // ---- V epilogue: [b][h][d][t], coalesced t-runs ----
    unsigned short* Tw = smem + wid * 2176;   // 32 x 68 (4 waves -> fits 32 KB)
#pragma unroll
    for (int h2 = 0; h2 < 2; ++h2) {
#pragma unroll
      for (int jj = 0; jj < 2; ++jj) {
        const int j = h2 * 2 + jj;
#pragma unroll
        for (int i = 0; i < 4; ++i)
#pragma unroll
          for (int r = 0; r < 4; ++r)
            Tw[(jj * 16 + ll) * 68 + i * 16 + lg * 4 + r] = f2bf((acc[i][j][r] + bj[j]) * scale);
      }
      asm volatile("s_waitcnt lgkmcnt(0)" ::: "memory");
#pragma unroll
      for (int k = 0; k < 8; ++k) {
        const int dloc = k * 4 + lg;
        const int t4   = ll * 4;
        const ushort4 vv = *(const ushort4*)&Tw[dloc * 68 + t4];
        const int n = nn + h2 * 32 + dloc;
        const int h = n >> 6, dd = n & 63;
        *(ushort4*)((unsigned short*)out + (long)b * sb + (long)h * sh + (long)dd * sd + tbs + t4) = vv;
      }
      if (h2 == 0) asm volatile("s_waitcnt lgkmcnt(0)" ::: "memory");
    }
    return;
  }

  if (OUT_BF16) {
    // ---- Q/K epilogue: [b][h][t][d], coalesced d-runs via LDS transpose ----
    const int h = nn >> 6;
    unsigned short* ob = (unsigned short*)out + (long)b * sb + (long)h * sh;
    unsigned short* Tw = smem + wid * 2176;   // 32 x 68
#pragma unroll
    for (int p = 0; p < 2; ++p) {
#pragma unroll
      for (int i2 = 0; i2 < 2; ++i2) {
        const int i = p * 2 + i2;
#pragma unroll
        for (int j = 0; j < 4; ++j)
#pragma unroll
          for (int r = 0; r < 4; ++r)
            Tw[(i2 * 16 + lg * 4 + r) * 68 + j * 16 + ll] = f2bf((acc[i][j][r] + bj[j]) * scale);
      }
      asm volatile("s_waitcnt lgkmcnt(0)" ::: "memory");
#pragma unroll
      for (int k = 0; k < 8; ++k) {
        const int t_loc = k * 4 + lg;
        const int d4    = ll * 4;
        const ushort4 vv = *(const ushort4*)&Tw[t_loc * 68 + d4];
        *(ushort4*)(ob + (long)(tbs + p * 32 + t_loc) * st + d4) = vv;
      }
      if (p == 0) asm volatile("s_waitcnt lgkmcnt(0)" ::: "memory");
    }
    return;
  }

  // ---- O epilogue (fp32): coalesced float2 runs ----
  {
    float* ob = (float*)out + (long)b * sb + nn;
    float* TwF = (float*)smem + wid * 1056;   // 16 x 66
#pragma unroll
    for (int i = 0; i < 4; ++i) {
#pragma unroll
      for (int j = 0; j < 4; ++j)
#pragma unroll
        for (int r = 0; r < 4; ++r)
          TwF[(lg * 4 + r) * 66 + j * 16 + ll] = acc[i][j][r] + bj[j];
      asm volatile("s_waitcnt lgkmcnt(0)" ::: "memory");
#pragma unroll
      for (int k = 0; k < 8; ++k) {
        const int t_loc = k * 2 + (lane >> 5);
        const int c2    = (lane & 31) * 2;
        const float2 v = *(const float2*)&TwF[t_loc * 66 + c2];
        *(float2*)(ob + (long)(tbs + i * 16 + t_loc) * st + c2) = v;
      }
      if (i < 3) asm volatile("s_waitcnt lgkmcnt(0)" ::: "memory");
    }
  }
}

struct GemmDesc {
  const unsigned short* A;
  const unsigned short* W;
  const float* bias;
  unsigned short* out;
  float scale;
  int log2R;
  long sb, st, sh, sd;
};

// fused Q/K/V projections, flat grid 1280 with XCD swizzle
__global__ __launch_bounds__(256) void gemm_qkv(GemmDesc d0, GemmDesc d1, GemmDesc d2) {
  int bid = xcd_swz(blockIdx.x, 160);
  const GemmDesc* d;
  bool vt = false;
  if (bid < 256)      { d = &d0; }
  else if (bid < 768) { d = &d1; bid -= 256; }
  else                { d = &d2; bid -= 768; vt = true; }
  gemm_core<true>(d->A, d->W, d->bias, d->out, d->scale, d->log2R,
                  d->sb, d->st, d->sh, d->sd, bid >> 3, bid & 7, vt);
}

// output projection (fp32 out), flat grid 256 with XCD swizzle
__global__ __launch_bounds__(256) void gemm_o(
    const unsigned short* __restrict__ A,
    const unsigned short* __restrict__ W,
    const float* __restrict__ bias,
    float* __restrict__ out,
    long sb, long st, long sh, long sd)
{
  const int bid = xcd_swz(blockIdx.x, 32);
  gemm_core<false>(A, W, bias, out, 1.0f, 10, sb, st, sh, sd, bid >> 3, bid & 7, false);
}

// ---------------- fused flash attention, swapped-QK^T, 8-wave blocks ----------------
// Qb: [B*H, T, 64] bf16 (pre-scaled 1/8); Kb: [B*H, S, 64]; Vt: [B*H, 64, S]
// bias fp32 [B*H,T,S]; Ob: [B*H, T, 64] bf16
// R9 structure (best measured) + T5 s_setprio around the MFMA clusters.
__global__ __launch_bounds__(512, 4) void attn_fused(
    const unsigned short* __restrict__ Qb,
    const unsigned short* __restrict__ Kb,
    const unsigned short* __restrict__ Vt,
    const float* __restrict__ bias,
    unsigned short* __restrict__ Ob)
{
  constexpr int T = 1024, S = 2048, NC = S / 64;
  __shared__ unsigned short Ks[64 * 72];      // [s][d] +8 pad
  __shared__ unsigned short Vs[64 * 72];      // [d][s] +8 pad
  __shared__ unsigned short Ps[8][16 * 72];   // per-wave P [t 16][s 64] +8 pad

  const int tid = threadIdx.x;
  const int w = tid >> 6, lane = tid & 63;
  const int lg = lane >> 4, ll = lane & 15;

  const int wg = xcd_swz(blockIdx.x, 64);    // 8 consecutive tiles of a bh per XCD
  const int bh = wg >> 3;
  const int tt = wg & 7;
  const int trow = tt * 128 + w * 16;        // this wave's 16 Q-rows

  // Q fragments (B-operand: col t = ll, k = d)
  bf16x8 qf[2];
#pragma unroll
  for (int ks = 0; ks < 2; ++ks)
    qf[ks] = *(const bf16x8*)(Qb + ((long)bh * T + trow + ll) * 64 + ks * 32 + lg * 8);

  f32x4 acc[4] = {};
  float m_run = -1e30f, l_run = 0.0f;

  const char* Kg = (const char*)(Kb + (long)bh * S * 64);
  const char* Vg = (const char*)(Vt + (long)bh * 64 * S);
  const float* bias_row = bias + ((long)bh * T + trow + ll) * S + lg * 4;
  unsigned short* Pw = &Ps[w][0];

  // staging addresses: 512 threads x (16B K + 16B V) per chunk
  const int srow = tid >> 3;          // 0..63
  const int scolb = (tid & 7) * 16;   // 0..112

  for (int sc = 0; sc < NC; ++sc) {
    // 1) issue bias loads first (independent; in flight across staging + barrier + QK^T)
    const float* bp = bias_row + sc * 64;
    f32x4 b4[4];
#pragma unroll
    for (int sf = 0; sf < 4; ++sf)
      b4[sf] = __builtin_nontemporal_load((const f32x4*)(bp + sf * 16));

    // 2) stage K [64 s][64 d] and V^T [64 d][64 s] into padded LDS
    {
      const uint4 kd = *(const uint4*)(Kg + (long)(sc * 64 + srow) * 128 + scolb);
      *(uint4*)((char*)&Ks[0] + srow * 144 + scolb) = kd;
      const uint4 vd = *(const uint4*)(Vg + (long)srow * (S * 2) + sc * 128 + scolb);
      *(uint4*)((char*)&Vs[0] + srow * 144 + scolb) = vd;
    }
    __syncthreads();

    // 3) swapped QK^T: lane holds (s = sf*16 + lg*4 + r, t = trow + ll)
    f32x4 sv[4] = {};
    __builtin_amdgcn_s_setprio(1);
#pragma unroll
    for (int ks = 0; ks < 2; ++ks) {
      bf16x8 kf[4];
#pragma unroll
      for (int sf = 0; sf < 4; ++sf)
        kf[sf] = *(const bf16x8*)((const char*)&Ks[0] + (sf * 16 + ll) * 144 + (ks * 32 + lg * 8) * 2);
#pragma unroll
      for (int sf = 0; sf < 4; ++sf)
        sv[sf] = __builtin_amdgcn_mfma_f32_16x16x32_bf16(kf[sf], qf[ks], sv[sf], 0, 0, 0);
    }
    __builtin_amdgcn_s_setprio(0);

#pragma unroll
    for (int sf = 0; sf < 4; ++sf) {
      sv[sf][0] += b4[sf][0]; sv[sf][1] += b4[sf][1];
      sv[sf][2] += b4[sf][2]; sv[sf][3] += b4[sf][3];
    }

    // 4) online softmax over s (16 in-reg + 2 shuffles)
    float cm = sv[0][0];
#pragma unroll
    for (int sf = 0; sf < 4; ++sf)
#pragma unroll
      for (int r = 0; r < 4; ++r) cm = fmaxf(cm, sv[sf][r]);
    cm = fmaxf(cm, __shfl_xor(cm, 16));
    cm = fmaxf(cm, __shfl_xor(cm, 32));

    const float mnew = fmaxf(m_run, cm);
    const float alpha = __expf(m_run - mnew);
    float ps = 0.0f;
#pragma unroll
    for (int sf = 0; sf < 4; ++sf)
#pragma unroll
      for (int r = 0; r < 4; ++r) {
        const float p = __expf(sv[sf][r] - mnew);
        sv[sf][r] = p;
        ps += p;
      }
    ps += __shfl_xor(ps, 16);
    ps += __shfl_xor(ps, 32);
    l_run = l_run * alpha + ps;
    m_run = mnew;

    float ar[4];
#pragma unroll
    for (int r = 0; r < 4; ++r) ar[r] = __shfl(alpha, lg * 4 + r);
#pragma unroll
    for (int df = 0; df < 4; ++df)
#pragma unroll
      for (int r = 0; r < 4; ++r) acc[df][r] *= ar[r];

    // 5) write P^T frags -> Ps[w] [t][s] (4x ds_write_b64)
#pragma unroll
    for (int sf = 0; sf < 4; ++sf) {
      ushort4 pw;
      pw.x = f2bf(sv[sf][0]); pw.y = f2bf(sv[sf][1]);
      pw.z = f2bf(sv[sf][2]); pw.w = f2bf(sv[sf][3]);
      *(ushort4*)&Pw[ll * 72 + sf * 16 + lg * 4] = pw;
    }
    asm volatile("s_waitcnt lgkmcnt(0)" ::: "memory");
    __builtin_amdgcn_sched_barrier(0);

    // 6) PV: acc[t][d] += P[t][s] * V[s][d]
    __builtin_amdgcn_s_setprio(1);
#pragma unroll
    for (int ks = 0; ks < 2; ++ks) {
      bf16x8 pa = *(const bf16x8*)((const char*)Pw + ll * 144 + ks * 64 + lg * 16);
      bf16x8 vf[4];
#pragma unroll
      for (int df = 0; df < 4; ++df)
        vf[df] = *(const bf16x8*)((const char*)&Vs[0] + (df * 16 + ll) * 144 + (ks * 32 + lg * 8) * 2);
#pragma unroll
      for (int df = 0; df < 4; ++df)
        acc[df] = __builtin_amdgcn_mfma_f32_16x16x32_bf16(pa, vf[df], acc[df], 0, 0, 0);
    }
    __builtin_amdgcn_s_setprio(0);
    __syncthreads();
  }

  // epilogue: normalize and store
  const float inv = 1.0f / l_run;
  float ir[4];
#pragma unroll
  for (int r = 0; r < 4; ++r) ir[r] = __shfl(inv, lg * 4 + r);
#pragma unroll
  for (int df = 0; df < 4; ++df)
#pragma unroll
    for (int r = 0; r < 4; ++r) {
      const long oo = ((long)bh * T + trow + lg * 4 + r) * 64 + df * 16 + ll;
      Ob[oo] = f2bf(acc[df][r] * ir[r]);
    }
}

// ---------------- host launch ----------------
extern "C" void kernel_launch(void* const* d_in, const int* in_sizes, int n_in,
                              void* d_out, int out_size, void* d_ws, size_t ws_size,
                              hipStream_t stream) {
  constexpr int B = 4, T = 1024, S = 2048, E = 1024;
  const float* hs   = (const float*)d_in[0];
  const float* kv   = (const float*)d_in[1];
  const float* bias = (const float*)d_in[2];
  const float* Wq   = (const float*)d_in[3];
  const float* bq   = (const float*)d_in[4];
  const float* Wk   = (const float*)d_in[5];
  const float* bk   = (const float*)d_in[6];
  const float* Wv   = (const float*)d_in[7];
  const float* bv   = (const float*)d_in[8];
  const float* Wo   = (const float*)d_in[9];
  const float* bo   = (const float*)d_in[10];

  char* ws = (char*)d_ws;
  const size_t MB = 1024 * 1024;
  unsigned short* hs_bf = (unsigned short*)(ws);
  unsigned short* kv_bf = (unsigned short*)(ws + 8 * MB);
  unsigned short* wq_bf = (unsigned short*)(ws + 24 * MB);
  unsigned short* wk_bf = (unsigned short*)(ws + 26 * MB);
  unsigned short* wv_bf = (unsigned short*)(ws + 28 * MB);
  unsigned short* wo_bf = (unsigned short*)(ws + 30 * MB);
  unsigned short* q_buf = (unsigned short*)(ws + 32 * MB);
  unsigned short* k_buf = (unsigned short*)(ws + 40 * MB);
  unsigned short* v_buf = (unsigned short*)(ws + 56 * MB);
  unsigned short* a_buf = (unsigned short*)(ws + 72 * MB);

  CvtArgs ca;
  ca.src[0] = hs;  ca.dst[0] = hs_bf;
  ca.src[1] = kv;  ca.dst[1] = kv_bf;
  ca.src[2] = Wq;  ca.dst[2] = wq_bf;
  ca.src[3] = Wk;  ca.dst[3] = wk_bf;
  ca.src[4] = Wv;  ca.dst[4] = wv_bf;
  ca.src[5] = Wo;  ca.dst[5] = wo_bf;
  const int n4_hs = B * T * E / 4, n4_kv = B * S * E / 4, n4_w = E * E / 4;
  ca.cum[0] = 0;
  ca.cum[1] = n4_hs;
  ca.cum[2] = n4_hs + n4_kv;
  ca.cum[3] = n4_hs + n4_kv + n4_w;
  ca.cum[4] = n4_hs + n4_kv + 2 * n4_w;
  ca.cum[5] = n4_hs + n4_kv + 3 * n4_w;
  const int total4 = n4_hs + n4_kv + 4 * n4_w;
  cvt_all<<<dim3((total4 + 255) / 256), dim3(256), 0, stream>>>(ca, total4);

  GemmDesc dq{hs_bf, wq_bf, bq, q_buf, 0.125f, 10,
              (long)T * E, 64L, (long)T * 64, 1L};
  GemmDesc dk{kv_bf, wk_bf, bk, k_buf, 1.0f, 11,
              (long)S * E, 64L, (long)S * 64, 1L};
  GemmDesc dv{kv_bf, wv_bf, bv, v_buf, 1.0f, 11,
              (long)S * E, 1L, (long)S * 64, (long)S};
  gemm_qkv<<<dim3(1280), 256, 0, stream>>>(dq, dk, dv);

  attn_fused<<<dim3(512), dim3(512), 0, stream>>>(q_buf, k_buf, v_buf, bias, a_buf);

  gemm_o<<<dim3(256), 256, 0, stream>>>(
      a_buf, wo_bf, bo, (float*)d_out,
      (long)T * E, (long)E, 64L, 1L);
}

// Round 21
// 250.078 us; speedup vs baseline: 1.0942x; 1.0181x over previous
//
#include <hip/hip_runtime.h>

#define DEVI __device__ __forceinline__

typedef __attribute__((ext_vector_type(4))) float f32x4;
typedef __attribute__((ext_vector_type(8))) short bf16x8;

DEVI unsigned short f2bf(float f) {
  unsigned int u = __builtin_bit_cast(unsigned int, f);
  u += 0x7FFFu + ((u >> 16) & 1u);   // round-to-nearest-even
  return (unsigned short)(u >> 16);
}

DEVI void load_lds16(const void* g, void* l) {
  __builtin_amdgcn_global_load_lds(
      (__attribute__((address_space(1))) void*)g,
      (__attribute__((address_space(3))) void*)l,
      16, 0, 0);
}

// chunked XCD swizzle (bijective when nwg % 8 == 0)
DEVI int xcd_swz(int bid, int chunk) { return (bid & 7) * chunk + (bid >> 3); }

// ---------------- fused fp32 -> bf16 bulk convert (6 segments, 1 launch) ----------------
struct CvtArgs {
  const float* src[6];
  unsigned short* dst[6];
  int cum[6];
};

__global__ __launch_bounds__(256) void cvt_all(CvtArgs a, int total4) {
  int i = blockIdx.x * 256 + threadIdx.x;
  if (i >= total4) return;
  int s = 0;
#pragma unroll
  for (int k = 1; k < 6; ++k) s += (i >= a.cum[k]);
  const int j = i - a.cum[s];
  const f32x4 v = __builtin_nontemporal_load((const f32x4*)a.src[s] + j);
  ushort4 o;
  o.x = f2bf(v[0]); o.y = f2bf(v[1]); o.z = f2bf(v[2]); o.w = f2bf(v[3]);
  reinterpret_cast<ushort4*>(a.dst[s])[j] = o;
}

// ---------------- shared 128x128xK=1024 GEMM core, 2-PHASE double-buffer ----------------
// C = A @ W^T + bias. A: [M,1024] bf16; W: [1024,1024] bf16.
// T3 "minimum 2-phase": per K-step, issue NEXT tile's global_load_lds FIRST, then
// compute the CURRENT tile, then ONE __syncthreads (full drain + barrier -- correct
// by construction; drain ~free because the loads had a full compute phase in flight).
// BK=32: 2 x (A 8KB + W 8KB) buffers = 32 KB. Validated R20: -19 us vs serial staging.
template<bool OUT_BF16>
DEVI void gemm_core(const unsigned short* __restrict__ A,
                    const unsigned short* __restrict__ W,
                    const float* __restrict__ bias,
                    void* __restrict__ out,
                    float scale, int log2R,
                    long sb, long st, long sh, long sd,
                    int bx, int by, bool vt)
{
  constexpr int K = 1024, NT = K / 32;       // 32 K-tiles of 32
  __shared__ unsigned short smem[2 * 8192];   // 32 KB: 2 bufs x (A 8KB + W 8KB)

  const int tid  = threadIdx.x;
  const int wid  = tid >> 6;
  const int lane = tid & 63;
  const int m0 = bx * 128;
  const int n0 = by * 128;
  const int wr = (wid >> 1) * 64;
  const int wc = (wid & 1) * 64;
  const int lg = lane >> 4;
  const int ll = lane & 15;

  f32x4 acc[4][4] = {};

  const char* Ab = (const char*)A + (long)m0 * K * 2;
  const char* Wb = (const char*)W + (long)n0 * K * 2;
  const long rowstride = (long)K * 2;

  const int r_off = lane >> 2;          // row within 16-row chunk
  const int cb    = (lane & 3) * 16;    // col-byte 0..48

  auto stage = [&](int tile, int buf) {
    const long ktb = (long)tile * 64;
    char* base = (char*)smem + buf * 16384;
#pragma unroll
    for (int c = 0; c < 2; ++c) {
      const int ch  = 2 * wid + c;      // chunk 0..7
      const int row = ch * 16 + r_off;
      load_lds16(Ab + (long)row * rowstride + ktb + cb, base + ch * 1024);
      load_lds16(Wb + (long)row * rowstride + ktb + cb, base + 8192 + ch * 1024);
    }
  };

  auto compute = [&](int buf) {
    const char* base = (const char*)smem + buf * 16384;
    bf16x8 af[4], bfr[4];
#pragma unroll
    for (int i = 0; i < 4; ++i) {
      af[i]  = *(const bf16x8*)(base + (wr + i * 16 + ll) * 64 + lg * 16);
      bfr[i] = *(const bf16x8*)(base + 8192 + (wc + i * 16 + ll) * 64 + lg * 16);
    }
#pragma unroll
    for (int i = 0; i < 4; ++i)
#pragma unroll
      for (int j = 0; j < 4; ++j)
        acc[i][j] = __builtin_amdgcn_mfma_f32_16x16x32_bf16(af[i], bfr[j], acc[i][j], 0, 0, 0);
  };

  stage(0, 0);
  __syncthreads();
  for (int kt = 0; kt < NT; ++kt) {
    const int cur = kt & 1;
    if (kt + 1 < NT) stage(kt + 1, cur ^ 1);   // issue BEFORE compute: latency hides
    compute(cur);
    __syncthreads();                            // full drain + barrier (race-free)
  }

  const int Rmask  = (1 << log2R) - 1;
  const int m_base = m0 + wr;
  const int b   = m_base >> log2R;
  const int tbs = m_base & Rmask;
  const int nn  = n0 + wc;
  float bj[4];
#pragma unroll
  for (int j = 0; j < 4; ++j) bj[j] = bias[nn + j * 16 + ll];

  if (OUT_BF16 && vt) {
    // ---- V epilogue: [b][h][d][t], coalesced t-runs ----
    unsigned short* Tw = smem + wid * 2176;   // 32 x 68
#pragma unroll
    for (int h2 = 0; h2 < 2; ++h2) {
#pragma unroll
      for (int jj = 0; jj < 2; ++jj) {
        const int j = h2 * 2 + jj;
#pragma unroll
        for (int i = 0; i < 4; ++i)
#pragma unroll
          for (int r = 0; r < 4; ++r)
            Tw[(jj * 16 + ll) * 68 + i * 16 + lg * 4 + r] = f2bf((acc[i][j][r] + bj[j]) * scale);
      }
      asm volatile("s_waitcnt lgkmcnt(0)" ::: "memory");
#pragma unroll
      for (int k = 0; k < 8; ++k) {
        const int dloc = k * 4 + lg;
        const int t4   = ll * 4;
        const ushort4 vv = *(const ushort4*)&Tw[dloc * 68 + t4];
        const int n = nn + h2 * 32 + dloc;
        const int h = n >> 6, dd = n & 63;
        *(ushort4*)((unsigned short*)out + (long)b * sb + (long)h * sh + (long)dd * sd + tbs + t4) = vv;
      }
      if (h2 == 0) asm volatile("s_waitcnt lgkmcnt(0)" ::: "memory");
    }
    return;
  }

  if (OUT_BF16) {
    // ---- Q/K epilogue: [b][h][t][d], coalesced d-runs via LDS transpose ----
    const int h = nn >> 6;
    unsigned short* ob = (unsigned short*)out + (long)b * sb + (long)h * sh;
    unsigned short* Tw = smem + wid * 2176;   // 32 x 68
#pragma unroll
    for (int p = 0; p < 2; ++p) {
#pragma unroll
      for (int i2 = 0; i2 < 2; ++i2) {
        const int i = p * 2 + i2;
#pragma unroll
        for (int j = 0; j < 4; ++j)
#pragma unroll
          for (int r = 0; r < 4; ++r)
            Tw[(i2 * 16 + lg * 4 + r) * 68 + j * 16 + ll] = f2bf((acc[i][j][r] + bj[j]) * scale);
      }
      asm volatile("s_waitcnt lgkmcnt(0)" ::: "memory");
#pragma unroll
      for (int k = 0; k < 8; ++k) {
        const int t_loc = k * 4 + lg;
        const int d4    = ll * 4;
        const ushort4 vv = *(const ushort4*)&Tw[t_loc * 68 + d4];
        *(ushort4*)(ob + (long)(tbs + p * 32 + t_loc) * st + d4) = vv;
      }
      if (p == 0) asm volatile("s_waitcnt lgkmcnt(0)" ::: "memory");
    }
    return;
  }

  // ---- O epilogue (fp32): coalesced float2 runs ----
  {
    float* ob = (float*)out + (long)b * sb + nn;
    float* TwF = (float*)smem + wid * 1056;   // 16 x 66
#pragma unroll
    for (int i = 0; i < 4; ++i) {
#pragma unroll
      for (int j = 0; j < 4; ++j)
#pragma unroll
        for (int r = 0; r < 4; ++r)
          TwF[(lg * 4 + r) * 66 + j * 16 + ll] = acc[i][j][r] + bj[j];
      asm volatile("s_waitcnt lgkmcnt(0)" ::: "memory");
#pragma unroll
      for (int k = 0; k < 8; ++k) {
        const int t_loc = k * 2 + (lane >> 5);
        const int c2    = (lane & 31) * 2;
        const float2 v = *(const float2*)&TwF[t_loc * 66 + c2];
        *(float2*)(ob + (long)(tbs + i * 16 + t_loc) * st + c2) = v;
      }
      if (i < 3) asm volatile("s_waitcnt lgkmcnt(0)" ::: "memory");
    }
  }
}

struct GemmDesc {
  const unsigned short* A;
  const unsigned short* W;
  const float* bias;
  unsigned short* out;
  float scale;
  int log2R;
  long sb, st, sh, sd;
};

// fused Q/K/V projections, flat grid 1280 with XCD swizzle
__global__ __launch_bounds__(256) void gemm_qkv(GemmDesc d0, GemmDesc d1, GemmDesc d2) {
  int bid = xcd_swz(blockIdx.x, 160);
  const GemmDesc* d;
  bool vt = false;
  if (bid < 256)      { d = &d0; }
  else if (bid < 768) { d = &d1; bid -= 256; }
  else                { d = &d2; bid -= 768; vt = true; }
  gemm_core<true>(d->A, d->W, d->bias, d->out, d->scale, d->log2R,
                  d->sb, d->st, d->sh, d->sd, bid >> 3, bid & 7, vt);
}

// output projection (fp32 out), flat grid 256 with XCD swizzle
__global__ __launch_bounds__(256) void gemm_o(
    const unsigned short* __restrict__ A,
    const unsigned short* __restrict__ W,
    const float* __restrict__ bias,
    float* __restrict__ out,
    long sb, long st, long sh, long sd)
{
  const int bid = xcd_swz(blockIdx.x, 32);
  gemm_core<false>(A, W, bias, out, 1.0f, 10, sb, st, sh, sd, bid >> 3, bid & 7, false);
}

// ---------------- fused flash attention, swapped-QK^T, 8-wave blocks ----------------
// Qb: [B*H, T, 64] bf16 (pre-scaled 1/8); Kb: [B*H, S, 64]; Vt: [B*H, 64, S]
// bias fp32 [B*H,T,S]; Ob: [B*H, T, 64] bf16
// R9 structure + T5 setprio. Bias loads are now PLAIN (no nontemporal): R13's
// counters showed L3 retains ~40% of the bias stream across replays even with nt;
// dropping the hint lets L2/L3 keep more of the dominant 537MB stream warm.
__global__ __launch_bounds__(512, 4) void attn_fused(
    const unsigned short* __restrict__ Qb,
    const unsigned short* __restrict__ Kb,
    const unsigned short* __restrict__ Vt,
    const float* __restrict__ bias,
    unsigned short* __restrict__ Ob)
{
  constexpr int T = 1024, S = 2048, NC = S / 64;
  __shared__ unsigned short Ks[64 * 72];      // [s][d] +8 pad
  __shared__ unsigned short Vs[64 * 72];      // [d][s] +8 pad
  __shared__ unsigned short Ps[8][16 * 72];   // per-wave P [t 16][s 64] +8 pad

  const int tid = threadIdx.x;
  const int w = tid >> 6, lane = tid & 63;
  const int lg = lane >> 4, ll = lane & 15;

  const int wg = xcd_swz(blockIdx.x, 64);    // 8 consecutive tiles of a bh per XCD
  const int bh = wg >> 3;
  const int tt = wg & 7;
  const int trow = tt * 128 + w * 16;        // this wave's 16 Q-rows

  // Q fragments (B-operand: col t = ll, k = d)
  bf16x8 qf[2];
#pragma unroll
  for (int ks = 0; ks < 2; ++ks)
    qf[ks] = *(const bf16x8*)(Qb + ((long)bh * T + trow + ll) * 64 + ks * 32 + lg * 8);

  f32x4 acc[4] = {};
  float m_run = -1e30f, l_run = 0.0f;

  const char* Kg = (const char*)(Kb + (long)bh * S * 64);
  const char* Vg = (const char*)(Vt + (long)bh * 64 * S);
  const float* bias_row = bias + ((long)bh * T + trow + ll) * S + lg * 4;
  unsigned short* Pw = &Ps[w][0];

  // staging addresses: 512 threads x (16B K + 16B V) per chunk
  const int srow = tid >> 3;          // 0..63
  const int scolb = (tid & 7) * 16;   // 0..112

  for (int sc = 0; sc < NC; ++sc) {
    // 1) issue bias loads first (independent; in flight across staging + barrier + QK^T)
    const float* bp = bias_row + sc * 64;
    f32x4 b4[4];
#pragma unroll
    for (int sf = 0; sf < 4; ++sf)
      b4[sf] = *(const f32x4*)(bp + sf * 16);

    // 2) stage K [64 s][64 d] and V^T [64 d][64 s] into padded LDS
    {
      const uint4 kd = *(const uint4*)(Kg + (long)(sc * 64 + srow) * 128 + scolb);
      *(uint4*)((char*)&Ks[0] + srow * 144 + scolb) = kd;
      const uint4 vd = *(const uint4*)(Vg + (long)srow * (S * 2) + sc * 128 + scolb);
      *(uint4*)((char*)&Vs[0] + srow * 144 + scolb) = vd;
    }
    __syncthreads();

    // 3) swapped QK^T: lane holds (s = sf*16 + lg*4 + r, t = trow + ll)
    f32x4 sv[4] = {};
    __builtin_amdgcn_s_setprio(1);
#pragma unroll
    for (int ks = 0; ks < 2; ++ks) {
      bf16x8 kf[4];
#pragma unroll
      for (int sf = 0; sf < 4; ++sf)
        kf[sf] = *(const bf16x8*)((const char*)&Ks[0] + (sf * 16 + ll) * 144 + (ks * 32 + lg * 8) * 2);
#pragma unroll
      for (int sf = 0; sf < 4; ++sf)
        sv[sf] = __builtin_amdgcn_mfma_f32_16x16x32_bf16(kf[sf], qf[ks], sv[sf], 0, 0, 0);
    }
    __builtin_amdgcn_s_setprio(0);

#pragma unroll
    for (int sf = 0; sf < 4; ++sf) {
      sv[sf][0] += b4[sf][0]; sv[sf][1] += b4[sf][1];
      sv[sf][2] += b4[sf][2]; sv[sf][3] += b4[sf][3];
    }

    // 4) online softmax over s (16 in-reg + 2 shuffles)
    float cm = sv[0][0];
#pragma unroll
    for (int sf = 0; sf < 4; ++sf)
#pragma unroll
      for (int r = 0; r < 4; ++r) cm = fmaxf(cm, sv[sf][r]);
    cm = fmaxf(cm, __shfl_xor(cm, 16));
    cm = fmaxf(cm, __shfl_xor(cm, 32));

    const float mnew = fmaxf(m_run, cm);
    const float alpha = __expf(m_run - mnew);
    float ps = 0.0f;
#pragma unroll
    for (int sf = 0; sf < 4; ++sf)
#pragma unroll
      for (int r = 0; r < 4; ++r) {
        const float p = __expf(sv[sf][r] - mnew);
        sv[sf][r] = p;
        ps += p;
      }
    ps += __shfl_xor(ps, 16);
    ps += __shfl_xor(ps, 32);
    l_run = l_run * alpha + ps;
    m_run = mnew;

    float ar[4];
#pragma unroll
    for (int r = 0; r < 4; ++r) ar[r] = __shfl(alpha, lg * 4 + r);
#pragma unroll
    for (int df = 0; df < 4; ++df)
#pragma unroll
      for (int r = 0; r < 4; ++r) acc[df][r] *= ar[r];

    // 5) write P^T frags -> Ps[w] [t][s] (4x ds_write_b64)
#pragma unroll
    for (int sf = 0; sf < 4; ++sf) {
      ushort4 pw;
      pw.x = f2bf(sv[sf][0]); pw.y = f2bf(sv[sf][1]);
      pw.z = f2bf(sv[sf][2]); pw.w = f2bf(sv[sf][3]);
      *(ushort4*)&Pw[ll * 72 + sf * 16 + lg * 4] = pw;
    }
    asm volatile("s_waitcnt lgkmcnt(0)" ::: "memory");
    __builtin_amdgcn_sched_barrier(0);

    // 6) PV: acc[t][d] += P[t][s] * V[s][d]
    __builtin_amdgcn_s_setprio(1);
#pragma unroll
    for (int ks = 0; ks < 2; ++ks) {
      bf16x8 pa = *(const bf16x8*)((const char*)Pw + ll * 144 + ks * 64 + lg * 16);
      bf16x8 vf[4];
#pragma unroll
      for (int df = 0; df < 4; ++df)
        vf[df] = *(const bf16x8*)((const char*)&Vs[0] + (df * 16 + ll) * 144 + (ks * 32 + lg * 8) * 2);
#pragma unroll
      for (int df = 0; df < 4; ++df)
        acc[df] = __builtin_amdgcn_mfma_f32_16x16x32_bf16(pa, vf[df], acc[df], 0, 0, 0);
    }
    __builtin_amdgcn_s_setprio(0);
    __syncthreads();
  }

  // epilogue: normalize and store
  const float inv = 1.0f / l_run;
  float ir[4];
#pragma unroll
  for (int r = 0; r < 4; ++r) ir[r] = __shfl(inv, lg * 4 + r);
#pragma unroll
  for (int df = 0; df < 4; ++df)
#pragma unroll
    for (int r = 0; r < 4; ++r) {
      const long oo = ((long)bh * T + trow + lg * 4 + r) * 64 + df * 16 + ll;
      Ob[oo] = f2bf(acc[df][r] * ir[r]);
    }
}

// ---------------- host launch ----------------
extern "C" void kernel_launch(void* const* d_in, const int* in_sizes, int n_in,
                              void* d_out, int out_size, void* d_ws, size_t ws_size,
                              hipStream_t stream) {
  constexpr int B = 4, T = 1024, S = 2048, E = 1024;
  const float* hs   = (const float*)d_in[0];
  const float* kv   = (const float*)d_in[1];
  const float* bias = (const float*)d_in[2];
  const float* Wq   = (const float*)d_in[3];
  const float* bq   = (const float*)d_in[4];
  const float* Wk   = (const float*)d_in[5];
  const float* bk   = (const float*)d_in[6];
  const float* Wv   = (const float*)d_in[7];
  const float* bv   = (const float*)d_in[8];
  const float* Wo   = (const float*)d_in[9];
  const float* bo   = (const float*)d_in[10];

  char* ws = (char*)d_ws;
  const size_t MB = 1024 * 1024;
  unsigned short* hs_bf = (unsigned short*)(ws);
  unsigned short* kv_bf = (unsigned short*)(ws + 8 * MB);
  unsigned short* wq_bf = (unsigned short*)(ws + 24 * MB);
  unsigned short* wk_bf = (unsigned short*)(ws + 26 * MB);
  unsigned short* wv_bf = (unsigned short*)(ws + 28 * MB);
  unsigned short* wo_bf = (unsigned short*)(ws + 30 * MB);
  unsigned short* q_buf = (unsigned short*)(ws + 32 * MB);
  unsigned short* k_buf = (unsigned short*)(ws + 40 * MB);
  unsigned short* v_buf = (unsigned short*)(ws + 56 * MB);
  unsigned short* a_buf = (unsigned short*)(ws + 72 * MB);

  CvtArgs ca;
  ca.src[0] = hs;  ca.dst[0] = hs_bf;
  ca.src[1] = kv;  ca.dst[1] = kv_bf;
  ca.src[2] = Wq;  ca.dst[2] = wq_bf;
  ca.src[3] = Wk;  ca.dst[3] = wk_bf;
  ca.src[4] = Wv;  ca.dst[4] = wv_bf;
  ca.src[5] = Wo;  ca.dst[5] = wo_bf;
  const int n4_hs = B * T * E / 4, n4_kv = B * S * E / 4, n4_w = E * E / 4;
  ca.cum[0] = 0;
  ca.cum[1] = n4_hs;
  ca.cum[2] = n4_hs + n4_kv;
  ca.cum[3] = n4_hs + n4_kv + n4_w;
  ca.cum[4] = n4_hs + n4_kv + 2 * n4_w;
  ca.cum[5] = n4_hs + n4_kv + 3 * n4_w;
  const int total4 = n4_hs + n4_kv + 4 * n4_w;
  cvt_all<<<dim3((total4 + 255) / 256), dim3(256), 0, stream>>>(ca, total4);

  GemmDesc dq{hs_bf, wq_bf, bq, q_buf, 0.125f, 10,
              (long)T * E, 64L, (long)T * 64, 1L};
  GemmDesc dk{kv_bf, wk_bf, bk, k_buf, 1.0f, 11,
              (long)S * E, 64L, (long)S * 64, 1L};
  GemmDesc dv{kv_bf, wv_bf, bv, v_buf, 1.0f, 11,
              (long)S * E, 1L, (long)S * 64, (long)S};
  gemm_qkv<<<dim3(1280), 256, 0, stream>>>(dq, dk, dv);

  attn_fused<<<dim3(512), dim3(512), 0, stream>>>(q_buf, k_buf, v_buf, bias, a_buf);

  gemm_o<<<dim3(256), 256, 0, stream>>>(
      a_buf, wo_bf, bo, (float*)d_out,
      (long)T * E, (long)E, 64L, 1L);
}

// Round 22
// 248.359 us; speedup vs baseline: 1.1018x; 1.0069x over previous
//
#include <hip/hip_runtime.h>

#define DEVI __device__ __forceinline__

typedef __attribute__((ext_vector_type(4))) float f32x4;
typedef __attribute__((ext_vector_type(8))) short bf16x8;

DEVI unsigned short f2bf(float f) {
  unsigned int u = __builtin_bit_cast(unsigned int, f);
  u += 0x7FFFu + ((u >> 16) & 1u);   // round-to-nearest-even
  return (unsigned short)(u >> 16);
}

DEVI void load_lds16(const void* g, void* l) {
  __builtin_amdgcn_global_load_lds(
      (__attribute__((address_space(1))) void*)g,
      (__attribute__((address_space(3))) void*)l,
      16, 0, 0);
}

// chunked XCD swizzle (bijective when nwg % 8 == 0)
DEVI int xcd_swz(int bid, int chunk) { return (bid & 7) * chunk + (bid >> 3); }

// ---------------- fused fp32 -> bf16 bulk convert (6 segments, 1 launch) ----------------
// PLAIN loads (no nontemporal): sources are re-read every graph replay and fit in
// L3 (64 MB total) -- same L3-retention win as the attn bias stream (R21: -4.5 us).
struct CvtArgs {
  const float* src[6];
  unsigned short* dst[6];
  int cum[6];
};

__global__ __launch_bounds__(256) void cvt_all(CvtArgs a, int total4) {
  int i = blockIdx.x * 256 + threadIdx.x;
  if (i >= total4) return;
  int s = 0;
#pragma unroll
  for (int k = 1; k < 6; ++k) s += (i >= a.cum[k]);
  const int j = i - a.cum[s];
  const f32x4 v = *((const f32x4*)a.src[s] + j);
  ushort4 o;
  o.x = f2bf(v[0]); o.y = f2bf(v[1]); o.z = f2bf(v[2]); o.w = f2bf(v[3]);
  reinterpret_cast<ushort4*>(a.dst[s])[j] = o;
}

// ---------------- shared 128x128xK=1024 GEMM core, 2-PHASE double-buffer ----------------
// C = A @ W^T + bias. A: [M,1024] bf16; W: [1024,1024] bf16.
// T3 "minimum 2-phase": per K-step, issue NEXT tile's global_load_lds FIRST, then
// compute the CURRENT tile, then ONE __syncthreads (full drain + barrier -- correct
// by construction; drain ~free because the loads had a full compute phase in flight).
// BK=32: 2 x (A 8KB + W 8KB) buffers = 32 KB. Validated R20: -19 us vs serial staging.
template<bool OUT_BF16>
DEVI void gemm_core(const unsigned short* __restrict__ A,
                    const unsigned short* __restrict__ W,
                    const float* __restrict__ bias,
                    void* __restrict__ out,
                    float scale, int log2R,
                    long sb, long st, long sh, long sd,
                    int bx, int by, bool vt)
{
  constexpr int K = 1024, NT = K / 32;       // 32 K-tiles of 32
  __shared__ unsigned short smem[2 * 8192];   // 32 KB: 2 bufs x (A 8KB + W 8KB)

  const int tid  = threadIdx.x;
  const int wid  = tid >> 6;
  const int lane = tid & 63;
  const int m0 = bx * 128;
  const int n0 = by * 128;
  const int wr = (wid >> 1) * 64;
  const int wc = (wid & 1) * 64;
  const int lg = lane >> 4;
  const int ll = lane & 15;

  f32x4 acc[4][4] = {};

  const char* Ab = (const char*)A + (long)m0 * K * 2;
  const char* Wb = (const char*)W + (long)n0 * K * 2;
  const long rowstride = (long)K * 2;

  const int r_off = lane >> 2;          // row within 16-row chunk
  const int cb    = (lane & 3) * 16;    // col-byte 0..48

  auto stage = [&](int tile, int buf) {
    const long ktb = (long)tile * 64;
    char* base = (char*)smem + buf * 16384;
#pragma unroll
    for (int c = 0; c < 2; ++c) {
      const int ch  = 2 * wid + c;      // chunk 0..7
      const int row = ch * 16 + r_off;
      load_lds16(Ab + (long)row * rowstride + ktb + cb, base + ch * 1024);
      load_lds16(Wb + (long)row * rowstride + ktb + cb, base + 8192 + ch * 1024);
    }
  };

  auto compute = [&](int buf) {
    const char* base = (const char*)smem + buf * 16384;
    bf16x8 af[4], bfr[4];
#pragma unroll
    for (int i = 0; i < 4; ++i) {
      af[i]  = *(const bf16x8*)(base + (wr + i * 16 + ll) * 64 + lg * 16);
      bfr[i] = *(const bf16x8*)(base + 8192 + (wc + i * 16 + ll) * 64 + lg * 16);
    }
#pragma unroll
    for (int i = 0; i < 4; ++i)
#pragma unroll
      for (int j = 0; j < 4; ++j)
        acc[i][j] = __builtin_amdgcn_mfma_f32_16x16x32_bf16(af[i], bfr[j], acc[i][j], 0, 0, 0);
  };

  stage(0, 0);
  __syncthreads();
  for (int kt = 0; kt < NT; ++kt) {
    const int cur = kt & 1;
    if (kt + 1 < NT) stage(kt + 1, cur ^ 1);   // issue BEFORE compute: latency hides
    compute(cur);
    __syncthreads();                            // full drain + barrier (race-free)
  }

  const int Rmask  = (1 << log2R) - 1;
  const int m_base = m0 + wr;
  const int b   = m_base >> log2R;
  const int tbs = m_base & Rmask;
  const int nn  = n0 + wc;
  float bj[4];
#pragma unroll
  for (int j = 0; j < 4; ++j) bj[j] = bias[nn + j * 16 + ll];

  if (OUT_BF16 && vt) {
    // ---- V epilogue: [b][h][d][t], coalesced t-runs ----
    unsigned short* Tw = smem + wid * 2176;   // 32 x 68
#pragma unroll
    for (int h2 = 0; h2 < 2; ++h2) {
#pragma unroll
      for (int jj = 0; jj < 2; ++jj) {
        const int j = h2 * 2 + jj;
#pragma unroll
        for (int i = 0; i < 4; ++i)
#pragma unroll
          for (int r = 0; r < 4; ++r)
            Tw[(jj * 16 + ll) * 68 + i * 16 + lg * 4 + r] = f2bf((acc[i][j][r] + bj[j]) * scale);
      }
      asm volatile("s_waitcnt lgkmcnt(0)" ::: "memory");
#pragma unroll
      for (int k = 0; k < 8; ++k) {
        const int dloc = k * 4 + lg;
        const int t4   = ll * 4;
        const ushort4 vv = *(const ushort4*)&Tw[dloc * 68 + t4];
        const int n = nn + h2 * 32 + dloc;
        const int h = n >> 6, dd = n & 63;
        *(ushort4*)((unsigned short*)out + (long)b * sb + (long)h * sh + (long)dd * sd + tbs + t4) = vv;
      }
      if (h2 == 0) asm volatile("s_waitcnt lgkmcnt(0)" ::: "memory");
    }
    return;
  }

  if (OUT_BF16) {
    // ---- Q/K epilogue: [b][h][t][d], coalesced d-runs via LDS transpose ----
    const int h = nn >> 6;
    unsigned short* ob = (unsigned short*)out + (long)b * sb + (long)h * sh;
    unsigned short* Tw = smem + wid * 2176;   // 32 x 68
#pragma unroll
    for (int p = 0; p < 2; ++p) {
#pragma unroll
      for (int i2 = 0; i2 < 2; ++i2) {
        const int i = p * 2 + i2;
#pragma unroll
        for (int j = 0; j < 4; ++j)
#pragma unroll
          for (int r = 0; r < 4; ++r)
            Tw[(i2 * 16 + lg * 4 + r) * 68 + j * 16 + ll] = f2bf((acc[i][j][r] + bj[j]) * scale);
      }
      asm volatile("s_waitcnt lgkmcnt(0)" ::: "memory");
#pragma unroll
      for (int k = 0; k < 8; ++k) {
        const int t_loc = k * 4 + lg;
        const int d4    = ll * 4;
        const ushort4 vv = *(const ushort4*)&Tw[t_loc * 68 + d4];
        *(ushort4*)(ob + (long)(tbs + p * 32 + t_loc) * st + d4) = vv;
      }
      if (p == 0) asm volatile("s_waitcnt lgkmcnt(0)" ::: "memory");
    }
    return;
  }

  // ---- O epilogue (fp32): coalesced float2 runs ----
  {
    float* ob = (float*)out + (long)b * sb + nn;
    float* TwF = (float*)smem + wid * 1056;   // 16 x 66
#pragma unroll
    for (int i = 0; i < 4; ++i) {
#pragma unroll
      for (int j = 0; j < 4; ++j)
#pragma unroll
        for (int r = 0; r < 4; ++r)
          TwF[(lg * 4 + r) * 66 + j * 16 + ll] = acc[i][j][r] + bj[j];
      asm volatile("s_waitcnt lgkmcnt(0)" ::: "memory");
#pragma unroll
      for (int k = 0; k < 8; ++k) {
        const int t_loc = k * 2 + (lane >> 5);
        const int c2    = (lane & 31) * 2;
        const float2 v = *(const float2*)&TwF[t_loc * 66 + c2];
        *(float2*)(ob + (long)(tbs + i * 16 + t_loc) * st + c2) = v;
      }
      if (i < 3) asm volatile("s_waitcnt lgkmcnt(0)" ::: "memory");
    }
  }
}

struct GemmDesc {
  const unsigned short* A;
  const unsigned short* W;
  const float* bias;
  unsigned short* out;
  float scale;
  int log2R;
  long sb, st, sh, sd;
};

// fused Q/K/V projections, flat grid 1280 with XCD swizzle
__global__ __launch_bounds__(256) void gemm_qkv(GemmDesc d0, GemmDesc d1, GemmDesc d2) {
  int bid = xcd_swz(blockIdx.x, 160);
  const GemmDesc* d;
  bool vt = false;
  if (bid < 256)      { d = &d0; }
  else if (bid < 768) { d = &d1; bid -= 256; }
  else                { d = &d2; bid -= 768; vt = true; }
  gemm_core<true>(d->A, d->W, d->bias, d->out, d->scale, d->log2R,
                  d->sb, d->st, d->sh, d->sd, bid >> 3, bid & 7, vt);
}

// output projection (fp32 out), flat grid 256 with XCD swizzle
__global__ __launch_bounds__(256) void gemm_o(
    const unsigned short* __restrict__ A,
    const unsigned short* __restrict__ W,
    const float* __restrict__ bias,
    float* __restrict__ out,
    long sb, long st, long sh, long sd)
{
  const int bid = xcd_swz(blockIdx.x, 32);
  gemm_core<false>(A, W, bias, out, 1.0f, 10, sb, st, sh, sd, bid >> 3, bid & 7, false);
}

// ---------------- fused flash attention, swapped-QK^T, 8-wave blocks ----------------
// Qb: [B*H, T, 64] bf16 (pre-scaled 1/8); Kb: [B*H, S, 64]; Vt: [B*H, 64, S]
// bias fp32 [B*H,T,S]; Ob: [B*H, T, 64] bf16
// R9 structure + T5 setprio + plain bias loads (R21: L3 retention win).
__global__ __launch_bounds__(512, 4) void attn_fused(
    const unsigned short* __restrict__ Qb,
    const unsigned short* __restrict__ Kb,
    const unsigned short* __restrict__ Vt,
    const float* __restrict__ bias,
    unsigned short* __restrict__ Ob)
{
  constexpr int T = 1024, S = 2048, NC = S / 64;
  __shared__ unsigned short Ks[64 * 72];      // [s][d] +8 pad
  __shared__ unsigned short Vs[64 * 72];      // [d][s] +8 pad
  __shared__ unsigned short Ps[8][16 * 72];   // per-wave P [t 16][s 64] +8 pad

  const int tid = threadIdx.x;
  const int w = tid >> 6, lane = tid & 63;
  const int lg = lane >> 4, ll = lane & 15;

  const int wg = xcd_swz(blockIdx.x, 64);    // 8 consecutive tiles of a bh per XCD
  const int bh = wg >> 3;
  const int tt = wg & 7;
  const int trow = tt * 128 + w * 16;        // this wave's 16 Q-rows

  // Q fragments (B-operand: col t = ll, k = d)
  bf16x8 qf[2];
#pragma unroll
  for (int ks = 0; ks < 2; ++ks)
    qf[ks] = *(const bf16x8*)(Qb + ((long)bh * T + trow + ll) * 64 + ks * 32 + lg * 8);

  f32x4 acc[4] = {};
  float m_run = -1e30f, l_run = 0.0f;

  const char* Kg = (const char*)(Kb + (long)bh * S * 64);
  const char* Vg = (const char*)(Vt + (long)bh * 64 * S);
  const float* bias_row = bias + ((long)bh * T + trow + ll) * S + lg * 4;
  unsigned short* Pw = &Ps[w][0];

  // staging addresses: 512 threads x (16B K + 16B V) per chunk
  const int srow = tid >> 3;          // 0..63
  const int scolb = (tid & 7) * 16;   // 0..112

  for (int sc = 0; sc < NC; ++sc) {
    // 1) issue bias loads first (independent; in flight across staging + barrier + QK^T)
    const float* bp = bias_row + sc * 64;
    f32x4 b4[4];
#pragma unroll
    for (int sf = 0; sf < 4; ++sf)
      b4[sf] = *(const f32x4*)(bp + sf * 16);

    // 2) stage K [64 s][64 d] and V^T [64 d][64 s] into padded LDS
    {
      const uint4 kd = *(const uint4*)(Kg + (long)(sc * 64 + srow) * 128 + scolb);
      *(uint4*)((char*)&Ks[0] + srow * 144 + scolb) = kd;
      const uint4 vd = *(const uint4*)(Vg + (long)srow * (S * 2) + sc * 128 + scolb);
      *(uint4*)((char*)&Vs[0] + srow * 144 + scolb) = vd;
    }
    __syncthreads();

    // 3) swapped QK^T: lane holds (s = sf*16 + lg*4 + r, t = trow + ll)
    f32x4 sv[4] = {};
    __builtin_amdgcn_s_setprio(1);
#pragma unroll
    for (int ks = 0; ks < 2; ++ks) {
      bf16x8 kf[4];
#pragma unroll
      for (int sf = 0; sf < 4; ++sf)
        kf[sf] = *(const bf16x8*)((const char*)&Ks[0] + (sf * 16 + ll) * 144 + (ks * 32 + lg * 8) * 2);
#pragma unroll
      for (int sf = 0; sf < 4; ++sf)
        sv[sf] = __builtin_amdgcn_mfma_f32_16x16x32_bf16(kf[sf], qf[ks], sv[sf], 0, 0, 0);
    }
    __builtin_amdgcn_s_setprio(0);

#pragma unroll
    for (int sf = 0; sf < 4; ++sf) {
      sv[sf][0] += b4[sf][0]; sv[sf][1] += b4[sf][1];
      sv[sf][2] += b4[sf][2]; sv[sf][3] += b4[sf][3];
    }

    // 4) online softmax over s (16 in-reg + 2 shuffles)
    float cm = sv[0][0];
#pragma unroll
    for (int sf = 0; sf < 4; ++sf)
#pragma unroll
      for (int r = 0; r < 4; ++r) cm = fmaxf(cm, sv[sf][r]);
    cm = fmaxf(cm, __shfl_xor(cm, 16));
    cm = fmaxf(cm, __shfl_xor(cm, 32));

    const float mnew = fmaxf(m_run, cm);
    const float alpha = __expf(m_run - mnew);
    float ps = 0.0f;
#pragma unroll
    for (int sf = 0; sf < 4; ++sf)
#pragma unroll
      for (int r = 0; r < 4; ++r) {
        const float p = __expf(sv[sf][r] - mnew);
        sv[sf][r] = p;
        ps += p;
      }
    ps += __shfl_xor(ps, 16);
    ps += __shfl_xor(ps, 32);
    l_run = l_run * alpha + ps;
    m_run = mnew;

    float ar[4];
#pragma unroll
    for (int r = 0; r < 4; ++r) ar[r] = __shfl(alpha, lg * 4 + r);
#pragma unroll
    for (int df = 0; df < 4; ++df)
#pragma unroll
      for (int r = 0; r < 4; ++r) acc[df][r] *= ar[r];

    // 5) write P^T frags -> Ps[w] [t][s] (4x ds_write_b64)
#pragma unroll
    for (int sf = 0; sf < 4; ++sf) {
      ushort4 pw;
      pw.x = f2bf(sv[sf][0]); pw.y = f2bf(sv[sf][1]);
      pw.z = f2bf(sv[sf][2]); pw.w = f2bf(sv[sf][3]);
      *(ushort4*)&Pw[ll * 72 + sf * 16 + lg * 4] = pw;
    }
    asm volatile("s_waitcnt lgkmcnt(0)" ::: "memory");
    __builtin_amdgcn_sched_barrier(0);

    // 6) PV: acc[t][d] += P[t][s] * V[s][d]
    __builtin_amdgcn_s_setprio(1);
#pragma unroll
    for (int ks = 0; ks < 2; ++ks) {
      bf16x8 pa = *(const bf16x8*)((const char*)Pw + ll * 144 + ks * 64 + lg * 16);
      bf16x8 vf[4];
#pragma unroll
      for (int df = 0; df < 4; ++df)
        vf[df] = *(const bf16x8*)((const char*)&Vs[0] + (df * 16 + ll) * 144 + (ks * 32 + lg * 8) * 2);
#pragma unroll
      for (int df = 0; df < 4; ++df)
        acc[df] = __builtin_amdgcn_mfma_f32_16x16x32_bf16(pa, vf[df], acc[df], 0, 0, 0);
    }
    __builtin_amdgcn_s_setprio(0);
    __syncthreads();
  }

  // epilogue: normalize and store
  const float inv = 1.0f / l_run;
  float ir[4];
#pragma unroll
  for (int r = 0; r < 4; ++r) ir[r] = __shfl(inv, lg * 4 + r);
#pragma unroll
  for (int df = 0; df < 4; ++df)
#pragma unroll
    for (int r = 0; r < 4; ++r) {
      const long oo = ((long)bh * T + trow + lg * 4 + r) * 64 + df * 16 + ll;
      Ob[oo] = f2bf(acc[df][r] * ir[r]);
    }
}

// ---------------- host launch ----------------
extern "C" void kernel_launch(void* const* d_in, const int* in_sizes, int n_in,
                              void* d_out, int out_size, void* d_ws, size_t ws_size,
                              hipStream_t stream) {
  constexpr int B = 4, T = 1024, S = 2048, E = 1024;
  const float* hs   = (const float*)d_in[0];
  const float* kv   = (const float*)d_in[1];
  const float* bias = (const float*)d_in[2];
  const float* Wq   = (const float*)d_in[3];
  const float* bq   = (const float*)d_in[4];
  const float* Wk   = (const float*)d_in[5];
  const float* bk   = (const float*)d_in[6];
  const float* Wv   = (const float*)d_in[7];
  const float* bv   = (const float*)d_in[8];
  const float* Wo   = (const float*)d_in[9];
  const float* bo   = (const float*)d_in[10];

  char* ws = (char*)d_ws;
  const size_t MB = 1024 * 1024;
  unsigned short* hs_bf = (unsigned short*)(ws);
  unsigned short* kv_bf = (unsigned short*)(ws + 8 * MB);
  unsigned short* wq_bf = (unsigned short*)(ws + 24 * MB);
  unsigned short* wk_bf = (unsigned short*)(ws + 26 * MB);
  unsigned short* wv_bf = (unsigned short*)(ws + 28 * MB);
  unsigned short* wo_bf = (unsigned short*)(ws + 30 * MB);
  unsigned short* q_buf = (unsigned short*)(ws + 32 * MB);
  unsigned short* k_buf = (unsigned short*)(ws + 40 * MB);
  unsigned short* v_buf = (unsigned short*)(ws + 56 * MB);
  unsigned short* a_buf = (unsigned short*)(ws + 72 * MB);

  CvtArgs ca;
  ca.src[0] = hs;  ca.dst[0] = hs_bf;
  ca.src[1] = kv;  ca.dst[1] = kv_bf;
  ca.src[2] = Wq;  ca.dst[2] = wq_bf;
  ca.src[3] = Wk;  ca.dst[3] = wk_bf;
  ca.src[4] = Wv;  ca.dst[4] = wv_bf;
  ca.src[5] = Wo;  ca.dst[5] = wo_bf;
  const int n4_hs = B * T * E / 4, n4_kv = B * S * E / 4, n4_w = E * E / 4;
  ca.cum[0] = 0;
  ca.cum[1] = n4_hs;
  ca.cum[2] = n4_hs + n4_kv;
  ca.cum[3] = n4_hs + n4_kv + n4_w;
  ca.cum[4] = n4_hs + n4_kv + 2 * n4_w;
  ca.cum[5] = n4_hs + n4_kv + 3 * n4_w;
  const int total4 = n4_hs + n4_kv + 4 * n4_w;
  cvt_all<<<dim3((total4 + 255) / 256), dim3(256), 0, stream>>>(ca, total4);

  GemmDesc dq{hs_bf, wq_bf, bq, q_buf, 0.125f, 10,
              (long)T * E, 64L, (long)T * 64, 1L};
  GemmDesc dk{kv_bf, wk_bf, bk, k_buf, 1.0f, 11,
              (long)S * E, 64L, (long)S * 64, 1L};
  GemmDesc dv{kv_bf, wv_bf, bv, v_buf, 1.0f, 11,
              (long)S * E, 1L, (long)S * 64, (long)S};
  gemm_qkv<<<dim3(1280), 256, 0, stream>>>(dq, dk, dv);

  attn_fused<<<dim3(512), dim3(512), 0, stream>>>(q_buf, k_buf, v_buf, bias, a_buf);

  gemm_o<<<dim3(256), 256, 0, stream>>>(
      a_buf, wo_bf, bo, (float*)d_out,
      (long)T * E, (long)E, 64L, 1L);
}